// Round 3
// baseline (6182.644 us; speedup 1.0000x reference)
//
#include <hip/hip_runtime.h>
#include <stdint.h>

#define D 512
#define T 2048      // S * var_num = 8 * 256
#define VOCAB 32000
#define NWG 16      // LSTM workgroups

typedef __attribute__((ext_vector_type(8))) short short8;
typedef __attribute__((ext_vector_type(4))) float f32x4;
typedef __attribute__((ext_vector_type(8))) unsigned short u16x8;

__device__ __forceinline__ float fast_rcp(float x) { return __builtin_amdgcn_rcpf(x); }
__device__ __forceinline__ float sigm(float x) { return fast_rcp(1.0f + __expf(-x)); }
__device__ __forceinline__ float tanh_fast(float x) {
  float e = __expf(2.0f * x);
  return 1.0f - 2.0f * fast_rcp(e + 1.0f);  // saturates correctly at +-1, no NaN
}
__device__ __forceinline__ unsigned short f2bf(float f) {  // RTNE float->bf16
  unsigned u = __float_as_uint(f);
  unsigned r = u + 0x7fffu + ((u >> 16) & 1u);
  return (unsigned short)(r >> 16);
}
__device__ __forceinline__ uint64_t AL(const uint64_t* p) {
  return __hip_atomic_load(p, __ATOMIC_RELAXED, __HIP_MEMORY_SCOPE_AGENT);
}

// ---------------------------------------------------------------------------
// Kernel 1: merged = ctx @ Wm + bm ; xz = merged @ W + b   (per 4-row block)
// x_seq is merged tiled 8x, so xz only needs the 256 base rows.
// ---------------------------------------------------------------------------
__global__ __launch_bounds__(512) void prep_kernel(
    const float* __restrict__ ctx, const float* __restrict__ Wm,
    const float* __restrict__ bm, const float* __restrict__ W,
    const float* __restrict__ b, float* __restrict__ xz)
{
  __shared__ float ctx_s[4][1024];
  __shared__ float mg_s[4][512];
  const int tid = threadIdx.x;
  const int r0 = blockIdx.x * 4;

  for (int i = tid; i < 1024; i += 512) {  // 4 rows * 256 float4 chunks
    int rr = i >> 8, c4 = (i & 255) * 4;
    *(float4*)&ctx_s[rr][c4] = *(const float4*)&ctx[(size_t)(r0 + rr) * 1024 + c4];
  }
  __syncthreads();
  {  // merged: thread -> (row rr, 4 consecutive cols)
    const int rr = tid >> 7, cg = (tid & 127) * 4;
    float a0 = bm[cg], a1 = bm[cg + 1], a2 = bm[cg + 2], a3 = bm[cg + 3];
    for (int k = 0; k < 1024; k += 4) {
      float4 cv = *(float4*)&ctx_s[rr][k];
      #pragma unroll
      for (int kk = 0; kk < 4; kk++) {
        float cc = (kk == 0) ? cv.x : (kk == 1) ? cv.y : (kk == 2) ? cv.z : cv.w;
        float4 wv = *(const float4*)&Wm[(size_t)(k + kk) * 512 + cg];
        a0 += cc * wv.x; a1 += cc * wv.y; a2 += cc * wv.z; a3 += cc * wv.w;
      }
    }
    *(float4*)&mg_s[rr][cg] = make_float4(a0, a1, a2, a3);
  }
  __syncthreads();
  {  // xz: thread -> (row rr, 16 consecutive cols of 2048)
    const int rr = tid >> 7, cg = (tid & 127) * 16;
    float acc[16];
    #pragma unroll
    for (int c = 0; c < 16; c++) acc[c] = b[cg + c];
    for (int k = 0; k < 512; k += 4) {
      float4 mv = *(float4*)&mg_s[rr][k];
      #pragma unroll
      for (int kk = 0; kk < 4; kk++) {
        float cc = (kk == 0) ? mv.x : (kk == 1) ? mv.y : (kk == 2) ? mv.z : mv.w;
        #pragma unroll
        for (int c4 = 0; c4 < 4; c4++) {
          float4 wv = *(const float4*)&W[(size_t)(k + kk) * 2048 + cg + c4 * 4];
          acc[c4 * 4 + 0] += cc * wv.x; acc[c4 * 4 + 1] += cc * wv.y;
          acc[c4 * 4 + 2] += cc * wv.z; acc[c4 * 4 + 3] += cc * wv.w;
        }
      }
    }
    #pragma unroll
    for (int c4 = 0; c4 < 4; c4++)
      *(float4*)&xz[(size_t)(r0 + rr) * 2048 + cg + c4 * 4] =
          make_float4(acc[c4 * 4], acc[c4 * 4 + 1], acc[c4 * 4 + 2], acc[c4 * 4 + 3]);
  }
}

// ---------------------------------------------------------------------------
// Kernel 2: Wlt[c][k] = bf16(Wl[k][c])  (transposed + converted for MFMA B)
// ---------------------------------------------------------------------------
__global__ __launch_bounds__(256) void wl_convert_kernel(
    const float* __restrict__ Wl, unsigned short* __restrict__ Wlt)
{
  const int c = blockIdx.x * 256 + threadIdx.x;
  for (int k8 = 0; k8 < 64; k8++) {
    u16x8 v;
    #pragma unroll
    for (int e = 0; e < 8; e++)
      v[e] = f2bf(Wl[(size_t)(k8 * 8 + e) * VOCAB + c]);
    *(u16x8*)&Wlt[(size_t)c * 512 + k8 * 8] = v;
  }
}

// ---------------------------------------------------------------------------
// Kernel 3: sequential LSTM over T steps. 16 WGs x 512 threads (cooperative).
// Group cb (= tid>>5, 32 lanes) owns 2 units x 4 gates: cols
//   col(c) = (c>>1)*512 + wg*32 + cb*2 + (c&1), c = 0..7.
// Thread holds U rows {rb+32e, e=0..15} x those 8 cols, PINNED in VGPRs via
// opaque asm (R2 bug: compiler kept only 92 VGPRs -> re-loaded U every step).
// After the 32-lane xor-reduce the gate lane (rb==0) has all 4 gates of its
// 2 units -> computes gates + stores h immediately (no z_lds, no mid barrier).
// Cross-WG h exchange: packed u64 {tag=t+1 | f32 h}, agent scope, parity
// double-buffered, 4-deep pipelined poll (detect granularity ~latency/4).
// ---------------------------------------------------------------------------
__global__ __launch_bounds__(512, 1) void lstm_kernel(
    const float* __restrict__ xz, const float* __restrict__ U,
    uint64_t* __restrict__ hb, unsigned short* __restrict__ hs)
{
  __shared__ float h_lds[512];
  const int tid = threadIdx.x;
  const int wg = blockIdx.x;
  const int rb = tid & 31;
  const int cb = tid >> 5;
  const int u0 = wg * 32 + cb * 2;   // first of this group's 2 units
  const bool gl = (rb == 0);         // gate lane (lane 0 / 32 of each wave)

  // one-time U load (scattered pairs; ~16 MB total across grid, one-shot)
  float u[16][8];
  #pragma unroll
  for (int e = 0; e < 16; e++) {
    const float* up = &U[(size_t)(rb + 32 * e) * 2048 + u0];
    #pragma unroll
    for (int g = 0; g < 4; g++) {
      u[e][g * 2]     = up[g * 512];
      u[e][g * 2 + 1] = up[g * 512 + 1];
    }
  }
  #pragma unroll
  for (int e = 0; e < 16; e++) {
    #pragma unroll
    for (int c = 0; c < 8; c++) asm volatile("" : "+v"(u[e][c]));  // pin
  }

  float c0 = 0.0f, c1 = 0.0f;

  for (int t = 0; t < T; t++) {
    // xz for this group's 8 gate-cols (gate lane only; hidden under poll)
    float xv[8];
    if (gl) {
      const float* xp = &xz[(size_t)(t & 255) * 2048 + u0];
      #pragma unroll
      for (int g = 0; g < 4; g++) { xv[g * 2] = xp[g * 512]; xv[g * 2 + 1] = xp[g * 512 + 1]; }
    }
    // pipelined poll of unit `tid` for step t
    {
      const uint64_t* hw = hb + (size_t)((t & 1) << 9) + tid;
      uint64_t v0 = AL(hw), v1 = AL(hw), v2 = AL(hw), v3 = AL(hw);
      float hval;
      for (;;) {
        if ((unsigned)(v0 >> 32) == (unsigned)t) { hval = __uint_as_float((unsigned)v0); break; }
        v0 = AL(hw);
        if ((unsigned)(v1 >> 32) == (unsigned)t) { hval = __uint_as_float((unsigned)v1); break; }
        v1 = AL(hw);
        if ((unsigned)(v2 >> 32) == (unsigned)t) { hval = __uint_as_float((unsigned)v2); break; }
        v2 = AL(hw);
        if ((unsigned)(v3 >> 32) == (unsigned)t) { hval = __uint_as_float((unsigned)v3); break; }
        v3 = AL(hw);
      }
      h_lds[tid] = hval;
    }
    __syncthreads();  // A: h_lds complete

    float zp[8];
    #pragma unroll
    for (int c = 0; c < 8; c++) zp[c] = 0.0f;
    #pragma unroll
    for (int e = 0; e < 16; e++) {
      float hv = h_lds[rb + 32 * e];  // bank rb, broadcast in upper half-wave
      #pragma unroll
      for (int c = 0; c < 8; c++) zp[c] = __builtin_fmaf(hv, u[e][c], zp[c]);
    }
    #pragma unroll
    for (int m = 1; m < 32; m <<= 1) {
      #pragma unroll
      for (int c = 0; c < 8; c++) zp[c] += __shfl_xor(zp[c], m, 64);
    }

    if (gl) {  // gates for units u0, u0+1: i,f,g,o = zp[0..1],[2..3],[4..5],[6..7]
      float i0 = sigm(zp[0] + xv[0]), i1 = sigm(zp[1] + xv[1]);
      float f0 = sigm(zp[2] + xv[2]), f1 = sigm(zp[3] + xv[3]);
      float g0 = tanh_fast(zp[4] + xv[4]), g1 = tanh_fast(zp[5] + xv[5]);
      float o0 = sigm(zp[6] + xv[6]), o1 = sigm(zp[7] + xv[7]);
      c0 = f0 * c0 + i0 * g0;
      c1 = f1 * c1 + i1 * g1;
      float h0 = o0 * tanh_fast(c0);
      float h1 = o1 * tanh_fast(c1);
      uint64_t tag = ((uint64_t)(unsigned)(t + 1)) << 32;
      uint64_t* dst = hb + (size_t)(((t + 1) & 1) << 9) + u0;
      __hip_atomic_store(dst,     tag | (uint64_t)__float_as_uint(h0),
                         __ATOMIC_RELAXED, __HIP_MEMORY_SCOPE_AGENT);
      __hip_atomic_store(dst + 1, tag | (uint64_t)__float_as_uint(h1),
                         __ATOMIC_RELAXED, __HIP_MEMORY_SCOPE_AGENT);
      unsigned hp = (unsigned)f2bf(h0) | ((unsigned)f2bf(h1) << 16);
      *(unsigned*)&hs[(size_t)t * 512 + u0] = hp;
    }
    __syncthreads();  // C: h_lds reads done before next-iter writes
  }
}

// ---------------------------------------------------------------------------
// Kernel 4: logits = hs @ Wl + bl, bf16 MFMA 16x16x32, 128x128 tile, 4 waves.
// Output remap: gemm row t -> out row (t%256)*8 + t/256.
// ---------------------------------------------------------------------------
__global__ __launch_bounds__(256) void logits_kernel(
    const unsigned short* __restrict__ hs, const unsigned short* __restrict__ Wlt,
    const float* __restrict__ bl, float* __restrict__ out)
{
  __shared__ unsigned short As[128][40];  // [row][k] +8 pad
  __shared__ unsigned short Bs[128][40];  // [col][k] +8 pad
  const int tid = threadIdx.x;
  const int bx = blockIdx.x, by = blockIdx.y;
  const int lane = tid & 63, w = tid >> 6;
  const int wr = w >> 1, wc = w & 1;

  f32x4 acc[4][4];
  #pragma unroll
  for (int i = 0; i < 4; i++) {
    #pragma unroll
    for (int j = 0; j < 4; j++) acc[i][j] = (f32x4){0.0f, 0.0f, 0.0f, 0.0f};
  }

  for (int kk = 0; kk < 512; kk += 32) {
    #pragma unroll
    for (int i = 0; i < 2; i++) {
      int chunk = tid * 2 + i;          // 512 chunks of 16B
      int r = chunk >> 2, c8 = (chunk & 3) * 8;
      *(uint4*)&As[r][c8] = *(const uint4*)&hs[(size_t)(by * 128 + r) * 512 + kk + c8];
      *(uint4*)&Bs[r][c8] = *(const uint4*)&Wlt[(size_t)(bx * 128 + r) * 512 + kk + c8];
    }
    __syncthreads();
    short8 af[4], bf[4];
    #pragma unroll
    for (int fr = 0; fr < 4; fr++)
      af[fr] = *(const short8*)&As[wr * 64 + fr * 16 + (lane & 15)][(lane >> 4) * 8];
    #pragma unroll
    for (int fc = 0; fc < 4; fc++)
      bf[fc] = *(const short8*)&Bs[wc * 64 + fc * 16 + (lane & 15)][(lane >> 4) * 8];
    #pragma unroll
    for (int fr = 0; fr < 4; fr++) {
      #pragma unroll
      for (int fc = 0; fc < 4; fc++)
        acc[fr][fc] = __builtin_amdgcn_mfma_f32_16x16x32_bf16(af[fr], bf[fc], acc[fr][fc], 0, 0, 0);
    }
    __syncthreads();
  }

  #pragma unroll
  for (int fc = 0; fc < 4; fc++) {
    int col = bx * 128 + wc * 64 + fc * 16 + (lane & 15);
    float blv = bl[col];
    #pragma unroll
    for (int fr = 0; fr < 4; fr++) {
      int row0 = by * 128 + wr * 64 + fr * 16 + (lane >> 4) * 4;
      #pragma unroll
      for (int j = 0; j < 4; j++) {
        int row = row0 + j;
        int orow = (row & 255) * 8 + (row >> 8);
        out[(size_t)orow * VOCAB + col] = acc[fr][fc][j] + blv;
      }
    }
  }
}

// ---------------------------------------------------------------------------
extern "C" void kernel_launch(void* const* d_in, const int* in_sizes, int n_in,
                              void* d_out, int out_size, void* d_ws, size_t ws_size,
                              hipStream_t stream)
{
  const float* ctx = (const float*)d_in[0];
  const float* Wm  = (const float*)d_in[1];
  const float* bm  = (const float*)d_in[2];
  const float* W   = (const float*)d_in[3];
  const float* U   = (const float*)d_in[4];
  const float* b   = (const float*)d_in[5];
  const float* Wl  = (const float*)d_in[6];
  const float* bl  = (const float*)d_in[7];
  float* out = (float*)d_out;

  char* ws = (char*)d_ws;
  uint64_t* hb        = (uint64_t*)ws;                                  // 8 KB (2x512 u64)
  float* xz           = (float*)(ws + 65536);                           // 2 MB
  unsigned short* hs  = (unsigned short*)(ws + 65536 + (1 << 21));      // 2 MB
  unsigned short* Wlt = (unsigned short*)(ws + 65536 + (2 << 21));      // 32.77 MB

  hipMemsetAsync(hb, 0, 8192, stream);  // h_0 = 0 with tag 0 (both parities)
  prep_kernel<<<dim3(64), dim3(512), 0, stream>>>(ctx, Wm, bm, W, b, xz);
  wl_convert_kernel<<<dim3(125), dim3(256), 0, stream>>>(Wl, Wlt);

  void* args[] = { (void*)&xz, (void*)&U, (void*)&hb, (void*)&hs };
  hipLaunchCooperativeKernel((void*)lstm_kernel, dim3(NWG), dim3(512), args, 0, stream);

  logits_kernel<<<dim3(250, 16), dim3(256), 0, stream>>>(hs, Wlt, bl, out);
}

// Round 4
// 5415.028 us; speedup vs baseline: 1.1418x; 1.1418x over previous
//
#include <hip/hip_runtime.h>
#include <stdint.h>

#define D 512
#define T 2048      // S * var_num = 8 * 256
#define VOCAB 32000
#define NWG 16      // LSTM workgroups

typedef __attribute__((ext_vector_type(8))) short short8;
typedef __attribute__((ext_vector_type(4))) float f32x4;
typedef __attribute__((ext_vector_type(8))) unsigned short u16x8;

__device__ __forceinline__ float fast_rcp(float x) { return __builtin_amdgcn_rcpf(x); }
__device__ __forceinline__ float sigm(float x) { return fast_rcp(1.0f + __expf(-x)); }
__device__ __forceinline__ float tanh_fast(float x) {
  float e = __expf(2.0f * x);
  return 1.0f - 2.0f * fast_rcp(e + 1.0f);  // saturates correctly at +-1, no NaN
}
__device__ __forceinline__ unsigned short f2bf(float f) {  // RTNE float->bf16
  unsigned u = __float_as_uint(f);
  unsigned r = u + 0x7fffu + ((u >> 16) & 1u);
  return (unsigned short)(r >> 16);
}
__device__ __forceinline__ uint64_t AL(const uint64_t* p) {
  return __hip_atomic_load(p, __ATOMIC_RELAXED, __HIP_MEMORY_SCOPE_AGENT);
}

// ---------------------------------------------------------------------------
// Kernel 1: merged = ctx @ Wm + bm ; xz = merged @ W + b   (per 4-row block)
// x_seq is merged tiled 8x, so xz only needs the 256 base rows.
// ---------------------------------------------------------------------------
__global__ __launch_bounds__(512) void prep_kernel(
    const float* __restrict__ ctx, const float* __restrict__ Wm,
    const float* __restrict__ bm, const float* __restrict__ W,
    const float* __restrict__ b, float* __restrict__ xz)
{
  __shared__ float ctx_s[4][1024];
  __shared__ float mg_s[4][512];
  const int tid = threadIdx.x;
  const int r0 = blockIdx.x * 4;

  for (int i = tid; i < 1024; i += 512) {  // 4 rows * 256 float4 chunks
    int rr = i >> 8, c4 = (i & 255) * 4;
    *(float4*)&ctx_s[rr][c4] = *(const float4*)&ctx[(size_t)(r0 + rr) * 1024 + c4];
  }
  __syncthreads();
  {  // merged: thread -> (row rr, 4 consecutive cols)
    const int rr = tid >> 7, cg = (tid & 127) * 4;
    float a0 = bm[cg], a1 = bm[cg + 1], a2 = bm[cg + 2], a3 = bm[cg + 3];
    for (int k = 0; k < 1024; k += 4) {
      float4 cv = *(float4*)&ctx_s[rr][k];
      #pragma unroll
      for (int kk = 0; kk < 4; kk++) {
        float cc = (kk == 0) ? cv.x : (kk == 1) ? cv.y : (kk == 2) ? cv.z : cv.w;
        float4 wv = *(const float4*)&Wm[(size_t)(k + kk) * 512 + cg];
        a0 += cc * wv.x; a1 += cc * wv.y; a2 += cc * wv.z; a3 += cc * wv.w;
      }
    }
    *(float4*)&mg_s[rr][cg] = make_float4(a0, a1, a2, a3);
  }
  __syncthreads();
  {  // xz: thread -> (row rr, 16 consecutive cols of 2048)
    const int rr = tid >> 7, cg = (tid & 127) * 16;
    float acc[16];
    #pragma unroll
    for (int c = 0; c < 16; c++) acc[c] = b[cg + c];
    for (int k = 0; k < 512; k += 4) {
      float4 mv = *(float4*)&mg_s[rr][k];
      #pragma unroll
      for (int kk = 0; kk < 4; kk++) {
        float cc = (kk == 0) ? mv.x : (kk == 1) ? mv.y : (kk == 2) ? mv.z : mv.w;
        #pragma unroll
        for (int c4 = 0; c4 < 4; c4++) {
          float4 wv = *(const float4*)&W[(size_t)(k + kk) * 2048 + cg + c4 * 4];
          acc[c4 * 4 + 0] += cc * wv.x; acc[c4 * 4 + 1] += cc * wv.y;
          acc[c4 * 4 + 2] += cc * wv.z; acc[c4 * 4 + 3] += cc * wv.w;
        }
      }
    }
    #pragma unroll
    for (int c4 = 0; c4 < 4; c4++)
      *(float4*)&xz[(size_t)(r0 + rr) * 2048 + cg + c4 * 4] =
          make_float4(acc[c4 * 4], acc[c4 * 4 + 1], acc[c4 * 4 + 2], acc[c4 * 4 + 3]);
  }
}

// ---------------------------------------------------------------------------
// Kernel 2: Wlt[c][k] = bf16(Wl[k][c])  (transposed + converted for MFMA B)
// ---------------------------------------------------------------------------
__global__ __launch_bounds__(256) void wl_convert_kernel(
    const float* __restrict__ Wl, unsigned short* __restrict__ Wlt)
{
  const int c = blockIdx.x * 256 + threadIdx.x;
  for (int k8 = 0; k8 < 64; k8++) {
    u16x8 v;
    #pragma unroll
    for (int e = 0; e < 8; e++)
      v[e] = f2bf(Wl[(size_t)(k8 * 8 + e) * VOCAB + c]);
    *(u16x8*)&Wlt[(size_t)c * 512 + k8 * 8] = v;
  }
}

// ---------------------------------------------------------------------------
// Kernel 3: sequential LSTM over T steps. 16 WGs x 512 threads (cooperative).
// R2 structure: group cb (= tid>>5) owns 8 CONTIGUOUS cols of one gate:
//   gate = cb>>2, cols = gate*512 + wg*32 + (cb&3)*8 + {0..7}
// Thread holds U rows {rb+32e, e=0..15} x 8 cols in u[16][8] VGPRs.
// KEY FIX vs R2/R3: in-loop empty-asm pins ("+v" each element at top of every
// t-iteration) make all 128 values live across the backedge -> compiler CANNOT
// sink the U loads into the loop (R2/R3 silently re-loaded U from L2 every
// step; VGPR_Count 92/88 proved it). Verification: VGPR_Count must be >=160.
// Cross-WG h exchange: packed u64 {tag=t+1 | f32 h}, agent scope, parity
// double-buffered, 4-deep pipelined poll.
// ---------------------------------------------------------------------------
__global__ __launch_bounds__(512, 1) void lstm_kernel(
    const float* __restrict__ xz, const float* __restrict__ U,
    uint64_t* __restrict__ hb, unsigned short* __restrict__ hs)
{
  __shared__ float h_lds[512];
  __shared__ float z_lds[128];
  const int tid = threadIdx.x;
  const int wg = blockIdx.x;
  const int rb = tid & 31;
  const int cb = tid >> 5;
  const int gate = cb >> 2;
  const int gcol0 = gate * 512 + wg * 32 + (cb & 3) * 8;

  // one-time U load: rows {rb+32e} x 8 contiguous cols (2x dwordx4 per row)
  float u[16][8];
  #pragma unroll
  for (int e = 0; e < 16; e++) {
    const float* up = &U[(size_t)(rb + 32 * e) * 2048 + gcol0];
    float4 w0 = *(const float4*)up;
    float4 w1 = *(const float4*)(up + 4);
    u[e][0] = w0.x; u[e][1] = w0.y; u[e][2] = w0.z; u[e][3] = w0.w;
    u[e][4] = w1.x; u[e][5] = w1.y; u[e][6] = w1.z; u[e][7] = w1.w;
  }

  float creg = 0.0f;

  for (int t = 0; t < T; t++) {
    // pin U in VGPRs for this iteration (emits no instructions; forces
    // all 128 values live across the loop so loads cannot be sunk)
    #pragma unroll
    for (int e = 0; e < 16; e++) {
      #pragma unroll
      for (int c = 0; c < 8; c++) asm volatile("" : "+v"(u[e][c]));
    }
    float xzv0, xzv1, xzv2, xzv3;
    if (tid < 32) {  // prefetch this step's xz (independent of h)
      const float* xp = &xz[(size_t)(t & 255) * 2048 + wg * 32 + tid];
      xzv0 = xp[0]; xzv1 = xp[512]; xzv2 = xp[1024]; xzv3 = xp[1536];
    }
    // 4-deep pipelined poll of unit `tid` for step t
    {
      const uint64_t* hw = hb + (size_t)((t & 1) << 9) + tid;
      uint64_t v0 = AL(hw), v1 = AL(hw), v2 = AL(hw), v3 = AL(hw);
      float hval;
      for (;;) {
        if ((unsigned)(v0 >> 32) == (unsigned)t) { hval = __uint_as_float((unsigned)v0); break; }
        v0 = AL(hw);
        if ((unsigned)(v1 >> 32) == (unsigned)t) { hval = __uint_as_float((unsigned)v1); break; }
        v1 = AL(hw);
        if ((unsigned)(v2 >> 32) == (unsigned)t) { hval = __uint_as_float((unsigned)v2); break; }
        v2 = AL(hw);
        if ((unsigned)(v3 >> 32) == (unsigned)t) { hval = __uint_as_float((unsigned)v3); break; }
        v3 = AL(hw);
      }
      h_lds[tid] = hval;
    }
    __syncthreads();  // A: h_lds complete

    float zp[8];
    #pragma unroll
    for (int c = 0; c < 8; c++) zp[c] = 0.0f;
    #pragma unroll
    for (int e = 0; e < 16; e++) {
      float hv = h_lds[rb + 32 * e];  // bank rb; 2-lane alias is free
      #pragma unroll
      for (int c = 0; c < 8; c++) zp[c] = __builtin_fmaf(hv, u[e][c], zp[c]);
    }
    // reduce over the 32 threads sharing cb (xor masks stay in 32-lane group)
    #pragma unroll
    for (int m = 1; m < 32; m <<= 1) {
      #pragma unroll
      for (int c = 0; c < 8; c++) zp[c] += __shfl_xor(zp[c], m, 64);
    }
    if (rb == 0) {
      *(float4*)&z_lds[cb * 8]     = make_float4(zp[0], zp[1], zp[2], zp[3]);
      *(float4*)&z_lds[cb * 8 + 4] = make_float4(zp[4], zp[5], zp[6], zp[7]);
    }
    __syncthreads();  // B: z_lds complete
    if (tid < 32) {   // gates for unit u = tid (32-lane parallel gate phase)
      float zi = z_lds[tid]       + xzv0;
      float zf = z_lds[32 + tid]  + xzv1;
      float zg = z_lds[64 + tid]  + xzv2;
      float zo = z_lds[96 + tid]  + xzv3;
      float ig = sigm(zi), fg = sigm(zf), gg = tanh_fast(zg), og = sigm(zo);
      creg = fg * creg + ig * gg;
      float h = og * tanh_fast(creg);
      hs[(size_t)t * 512 + wg * 32 + tid] = f2bf(h);
      uint64_t pk = ((uint64_t)(unsigned)(t + 1) << 32) | (uint64_t)__float_as_uint(h);
      __hip_atomic_store(&hb[(size_t)(((t + 1) & 1) << 9) + wg * 32 + tid], pk,
                         __ATOMIC_RELAXED, __HIP_MEMORY_SCOPE_AGENT);
    }
  }
}

// ---------------------------------------------------------------------------
// Kernel 4: logits = hs @ Wl + bl, bf16 MFMA 16x16x32, 128x128 tile, 4 waves.
// Output remap: gemm row t -> out row (t%256)*8 + t/256.
// ---------------------------------------------------------------------------
__global__ __launch_bounds__(256) void logits_kernel(
    const unsigned short* __restrict__ hs, const unsigned short* __restrict__ Wlt,
    const float* __restrict__ bl, float* __restrict__ out)
{
  __shared__ unsigned short As[128][40];  // [row][k] +8 pad
  __shared__ unsigned short Bs[128][40];  // [col][k] +8 pad
  const int tid = threadIdx.x;
  const int bx = blockIdx.x, by = blockIdx.y;
  const int lane = tid & 63, w = tid >> 6;
  const int wr = w >> 1, wc = w & 1;

  f32x4 acc[4][4];
  #pragma unroll
  for (int i = 0; i < 4; i++) {
    #pragma unroll
    for (int j = 0; j < 4; j++) acc[i][j] = (f32x4){0.0f, 0.0f, 0.0f, 0.0f};
  }

  for (int kk = 0; kk < 512; kk += 32) {
    #pragma unroll
    for (int i = 0; i < 2; i++) {
      int chunk = tid * 2 + i;          // 512 chunks of 16B
      int r = chunk >> 2, c8 = (chunk & 3) * 8;
      *(uint4*)&As[r][c8] = *(const uint4*)&hs[(size_t)(by * 128 + r) * 512 + kk + c8];
      *(uint4*)&Bs[r][c8] = *(const uint4*)&Wlt[(size_t)(bx * 128 + r) * 512 + kk + c8];
    }
    __syncthreads();
    short8 af[4], bf[4];
    #pragma unroll
    for (int fr = 0; fr < 4; fr++)
      af[fr] = *(const short8*)&As[wr * 64 + fr * 16 + (lane & 15)][(lane >> 4) * 8];
    #pragma unroll
    for (int fc = 0; fc < 4; fc++)
      bf[fc] = *(const short8*)&Bs[wc * 64 + fc * 16 + (lane & 15)][(lane >> 4) * 8];
    #pragma unroll
    for (int fr = 0; fr < 4; fr++) {
      #pragma unroll
      for (int fc = 0; fc < 4; fc++)
        acc[fr][fc] = __builtin_amdgcn_mfma_f32_16x16x32_bf16(af[fr], bf[fc], acc[fr][fc], 0, 0, 0);
    }
    __syncthreads();
  }

  #pragma unroll
  for (int fc = 0; fc < 4; fc++) {
    int col = bx * 128 + wc * 64 + fc * 16 + (lane & 15);
    float blv = bl[col];
    #pragma unroll
    for (int fr = 0; fr < 4; fr++) {
      int row0 = by * 128 + wr * 64 + fr * 16 + (lane >> 4) * 4;
      #pragma unroll
      for (int j = 0; j < 4; j++) {
        int row = row0 + j;
        int orow = (row & 255) * 8 + (row >> 8);
        out[(size_t)orow * VOCAB + col] = acc[fr][fc][j] + blv;
      }
    }
  }
}

// ---------------------------------------------------------------------------
extern "C" void kernel_launch(void* const* d_in, const int* in_sizes, int n_in,
                              void* d_out, int out_size, void* d_ws, size_t ws_size,
                              hipStream_t stream)
{
  const float* ctx = (const float*)d_in[0];
  const float* Wm  = (const float*)d_in[1];
  const float* bm  = (const float*)d_in[2];
  const float* W   = (const float*)d_in[3];
  const float* U   = (const float*)d_in[4];
  const float* b   = (const float*)d_in[5];
  const float* Wl  = (const float*)d_in[6];
  const float* bl  = (const float*)d_in[7];
  float* out = (float*)d_out;

  char* ws = (char*)d_ws;
  uint64_t* hb        = (uint64_t*)ws;                                  // 8 KB (2x512 u64)
  float* xz           = (float*)(ws + 65536);                           // 2 MB
  unsigned short* hs  = (unsigned short*)(ws + 65536 + (1 << 21));      // 2 MB
  unsigned short* Wlt = (unsigned short*)(ws + 65536 + (2 << 21));      // 32.77 MB

  hipMemsetAsync(hb, 0, 8192, stream);  // h_0 = 0 with tag 0 (both parities)
  prep_kernel<<<dim3(64), dim3(512), 0, stream>>>(ctx, Wm, bm, W, b, xz);
  wl_convert_kernel<<<dim3(125), dim3(256), 0, stream>>>(Wl, Wlt);

  void* args[] = { (void*)&xz, (void*)&U, (void*)&hb, (void*)&hs };
  hipLaunchCooperativeKernel((void*)lstm_kernel, dim3(NWG), dim3(512), args, 0, stream);

  logits_kernel<<<dim3(250, 16), dim3(256), 0, stream>>>(hs, Wlt, bl, out);
}

// Round 6
// 5109.478 us; speedup vs baseline: 1.2100x; 1.0598x over previous
//
#include <hip/hip_runtime.h>
#include <stdint.h>

#define D 512
#define T 2048      // S * var_num = 8 * 256
#define VOCAB 32000
#define NWG 16      // LSTM workgroups

typedef __attribute__((ext_vector_type(8))) short short8;
typedef __attribute__((ext_vector_type(4))) float f32x4;
typedef __attribute__((ext_vector_type(8))) unsigned short u16x8;
typedef __attribute__((ext_vector_type(2))) __fp16 f16x2;   // matches cvt_pkrtz return

__device__ __forceinline__ float fast_rcp(float x) { return __builtin_amdgcn_rcpf(x); }
__device__ __forceinline__ float sigm(float x) { return fast_rcp(1.0f + __expf(-x)); }
__device__ __forceinline__ float tanh_fast(float x) {
  float e = __expf(2.0f * x);
  return 1.0f - 2.0f * fast_rcp(e + 1.0f);  // saturates correctly at +-1, no NaN
}
__device__ __forceinline__ unsigned short f2bf(float f) {  // RTNE float->bf16
  unsigned u = __float_as_uint(f);
  unsigned r = u + 0x7fffu + ((u >> 16) & 1u);
  return (unsigned short)(r >> 16);
}
__device__ __forceinline__ uint64_t AL(const uint64_t* p) {
  return __hip_atomic_load(p, __ATOMIC_RELAXED, __HIP_MEMORY_SCOPE_AGENT);
}
union U32H2 { unsigned u; f16x2 h; };

// ---------------------------------------------------------------------------
// Kernel 1: merged = ctx @ Wm + bm ; xz = merged @ W + b   (per 4-row block)
// ---------------------------------------------------------------------------
__global__ __launch_bounds__(512) void prep_kernel(
    const float* __restrict__ ctx, const float* __restrict__ Wm,
    const float* __restrict__ bm, const float* __restrict__ W,
    const float* __restrict__ b, float* __restrict__ xz)
{
  __shared__ float ctx_s[4][1024];
  __shared__ float mg_s[4][512];
  const int tid = threadIdx.x;
  const int r0 = blockIdx.x * 4;

  for (int i = tid; i < 1024; i += 512) {
    int rr = i >> 8, c4 = (i & 255) * 4;
    *(float4*)&ctx_s[rr][c4] = *(const float4*)&ctx[(size_t)(r0 + rr) * 1024 + c4];
  }
  __syncthreads();
  {
    const int rr = tid >> 7, cg = (tid & 127) * 4;
    float a0 = bm[cg], a1 = bm[cg + 1], a2 = bm[cg + 2], a3 = bm[cg + 3];
    for (int k = 0; k < 1024; k += 4) {
      float4 cv = *(float4*)&ctx_s[rr][k];
      #pragma unroll
      for (int kk = 0; kk < 4; kk++) {
        float cc = (kk == 0) ? cv.x : (kk == 1) ? cv.y : (kk == 2) ? cv.z : cv.w;
        float4 wv = *(const float4*)&Wm[(size_t)(k + kk) * 512 + cg];
        a0 += cc * wv.x; a1 += cc * wv.y; a2 += cc * wv.z; a3 += cc * wv.w;
      }
    }
    *(float4*)&mg_s[rr][cg] = make_float4(a0, a1, a2, a3);
  }
  __syncthreads();
  {
    const int rr = tid >> 7, cg = (tid & 127) * 16;
    float acc[16];
    #pragma unroll
    for (int c = 0; c < 16; c++) acc[c] = b[cg + c];
    for (int k = 0; k < 512; k += 4) {
      float4 mv = *(float4*)&mg_s[rr][k];
      #pragma unroll
      for (int kk = 0; kk < 4; kk++) {
        float cc = (kk == 0) ? mv.x : (kk == 1) ? mv.y : (kk == 2) ? mv.z : mv.w;
        #pragma unroll
        for (int c4 = 0; c4 < 4; c4++) {
          float4 wv = *(const float4*)&W[(size_t)(k + kk) * 2048 + cg + c4 * 4];
          acc[c4 * 4 + 0] += cc * wv.x; acc[c4 * 4 + 1] += cc * wv.y;
          acc[c4 * 4 + 2] += cc * wv.z; acc[c4 * 4 + 3] += cc * wv.w;
        }
      }
    }
    #pragma unroll
    for (int c4 = 0; c4 < 4; c4++)
      *(float4*)&xz[(size_t)(r0 + rr) * 2048 + cg + c4 * 4] =
          make_float4(acc[c4 * 4], acc[c4 * 4 + 1], acc[c4 * 4 + 2], acc[c4 * 4 + 3]);
  }
}

// ---------------------------------------------------------------------------
// Kernel 2: Wlt[c][k] = bf16(Wl[k][c])
// ---------------------------------------------------------------------------
__global__ __launch_bounds__(256) void wl_convert_kernel(
    const float* __restrict__ Wl, unsigned short* __restrict__ Wlt)
{
  const int c = blockIdx.x * 256 + threadIdx.x;
  for (int k8 = 0; k8 < 64; k8++) {
    u16x8 v;
    #pragma unroll
    for (int e = 0; e < 8; e++)
      v[e] = f2bf(Wl[(size_t)(k8 * 8 + e) * VOCAB + c]);
    *(u16x8*)&Wlt[(size_t)c * 512 + k8 * 8] = v;
  }
}

// ---------------------------------------------------------------------------
// Kernel 2b: Up[p][c] = pack_f16( U[(p>>5)*64 + (p&31)][c],
//                                 U[(p>>5)*64 + (p&31) + 32][c] )
// Row-paired packed-f16 U for the lstm's v_dot2 matvec.
// ---------------------------------------------------------------------------
__global__ __launch_bounds__(256) void uconv_kernel(
    const float* __restrict__ U, unsigned* __restrict__ Up)
{
  const int p = blockIdx.x;              // 0..255
  const int c0 = threadIdx.x * 8;        // 8 cols per thread
  const int r_lo = (p >> 5) * 64 + (p & 31);
  const float* lo = &U[(size_t)r_lo * 2048 + c0];
  const float* hi = &U[(size_t)(r_lo + 32) * 2048 + c0];
  unsigned outv[8];
  #pragma unroll
  for (int c = 0; c < 8; c++) {
    U32H2 w;
    w.h[0] = (__fp16)lo[c];
    w.h[1] = (__fp16)hi[c];
    outv[c] = w.u;
  }
  #pragma unroll
  for (int c4 = 0; c4 < 2; c4++)
    *(uint4*)&Up[(size_t)p * 2048 + c0 + c4 * 4] =
        make_uint4(outv[c4 * 4], outv[c4 * 4 + 1], outv[c4 * 4 + 2], outv[c4 * 4 + 3]);
}

// ---------------------------------------------------------------------------
// Kernel 3: sequential LSTM over T steps. 16 WGs x 512 threads (cooperative).
// R2 structure (2 barriers, parity-buffered hb, simple poll). Group cb owns
// 8 contiguous cols of one gate; thread holds U rows {rb+32e} x 8 cols as
// PACKED F16 PAIRS: u2[ep][c] = {U[64ep+rb][col], U[64ep+rb+32][col]}.
// Loaded ONCE via asm volatile global_load_dwordx4 (cannot be rematerialized
// -> R2/R3/R4's silent per-step U reload from L2, ~1.7us/step, is impossible).
// In-loop empty-asm pins keep all 64 u32 live across the backedge.
// Matvec: 8x cvt_pkrtz(h_pair) + 64x v_dot2_f32_f16.
// Verification signal: VGPR_Count >= 100 (was 92 when reloading).
// ---------------------------------------------------------------------------
__global__ __launch_bounds__(512, 1) void lstm_kernel(
    const float* __restrict__ xz, const unsigned* __restrict__ Up,
    uint64_t* __restrict__ hb, unsigned short* __restrict__ hs)
{
  __shared__ float h_lds[512];
  __shared__ float z_lds[128];
  const int tid = threadIdx.x;
  const int wg = blockIdx.x;
  const int rb = tid & 31;
  const int cb = tid >> 5;
  const int gate = cb >> 2;
  const int gcol0 = gate * 512 + wg * 32 + (cb & 3) * 8;

  // one-time exactly-once U load: 8 pairs x 8 cols = 16x dwordx4
  uint4 uv[16];
  #pragma unroll
  for (int ep = 0; ep < 8; ep++) {
    const unsigned* ap = &Up[(size_t)(ep * 32 + rb) * 2048 + gcol0];
    asm volatile("global_load_dwordx4 %0, %1, off"
                 : "=v"(uv[ep * 2]) : "v"(ap));
    asm volatile("global_load_dwordx4 %0, %1, off offset:16"
                 : "=v"(uv[ep * 2 + 1]) : "v"(ap));
  }
  asm volatile("s_waitcnt vmcnt(0)" ::: "memory");
  unsigned u2[8][8];
  #pragma unroll
  for (int ep = 0; ep < 8; ep++) {
    uint4 a = uv[ep * 2], b4 = uv[ep * 2 + 1];
    u2[ep][0] = a.x; u2[ep][1] = a.y; u2[ep][2] = a.z; u2[ep][3] = a.w;
    u2[ep][4] = b4.x; u2[ep][5] = b4.y; u2[ep][6] = b4.z; u2[ep][7] = b4.w;
  }

  float creg = 0.0f;

  for (int t = 0; t < T; t++) {
    // keep the 64 packed-U words live across the backedge (no instructions)
    #pragma unroll
    for (int ep = 0; ep < 8; ep++) {
      #pragma unroll
      for (int c = 0; c < 8; c++) asm volatile("" : "+v"(u2[ep][c]));
    }
    float xzv0, xzv1, xzv2, xzv3;
    if (tid < 32) {  // prefetch this step's xz (independent of h)
      const float* xp = &xz[(size_t)(t & 255) * 2048 + wg * 32 + tid];
      xzv0 = xp[0]; xzv1 = xp[512]; xzv2 = xp[1024]; xzv3 = xp[1536];
    }
    // poll ONE word: unit `tid` of h_t
    {
      const uint64_t* hw = hb + (size_t)((t & 1) << 9) + tid;
      uint64_t wv;
      for (;;) {
        wv = AL(hw);
        if ((unsigned)(wv >> 32) == (unsigned)t) break;
      }
      h_lds[tid] = __uint_as_float((unsigned)wv);
    }
    __syncthreads();  // A: h_lds complete

    float zp[8];
    #pragma unroll
    for (int c = 0; c < 8; c++) zp[c] = 0.0f;
    #pragma unroll
    for (int ep = 0; ep < 8; ep++) {
      float hlo = h_lds[rb + 64 * ep];        // bank rb, 2-lane broadcast
      float hhi = h_lds[rb + 64 * ep + 32];   // bank rb
      f16x2 h2 = __builtin_amdgcn_cvt_pkrtz(hlo, hhi);
      #pragma unroll
      for (int c = 0; c < 8; c++) {
        U32H2 w; w.u = u2[ep][c];
        zp[c] = __builtin_amdgcn_fdot2(h2, w.h, zp[c], false);
      }
    }
    // reduce over the 32 threads sharing cb (xor masks stay in 32-lane group)
    #pragma unroll
    for (int m = 1; m < 32; m <<= 1) {
      #pragma unroll
      for (int c = 0; c < 8; c++) zp[c] += __shfl_xor(zp[c], m, 64);
    }
    if (rb == 0) {
      *(float4*)&z_lds[cb * 8]     = make_float4(zp[0], zp[1], zp[2], zp[3]);
      *(float4*)&z_lds[cb * 8 + 4] = make_float4(zp[4], zp[5], zp[6], zp[7]);
    }
    __syncthreads();  // B: z_lds complete (also orders h_lds reads vs next write)
    if (tid < 32) {   // gates for unit u = tid
      float zi = z_lds[tid]       + xzv0;
      float zf = z_lds[32 + tid]  + xzv1;
      float zg = z_lds[64 + tid]  + xzv2;
      float zo = z_lds[96 + tid]  + xzv3;
      float ig = sigm(zi), fg = sigm(zf), gg = tanh_fast(zg), og = sigm(zo);
      creg = fg * creg + ig * gg;
      float h = og * tanh_fast(creg);
      hs[(size_t)t * 512 + wg * 32 + tid] = f2bf(h);
      uint64_t pk = ((uint64_t)(unsigned)(t + 1) << 32) | (uint64_t)__float_as_uint(h);
      __hip_atomic_store(&hb[(size_t)(((t + 1) & 1) << 9) + wg * 32 + tid], pk,
                         __ATOMIC_RELAXED, __HIP_MEMORY_SCOPE_AGENT);
    }
  }
}

// ---------------------------------------------------------------------------
// Kernel 4: logits = hs @ Wl + bl, bf16 MFMA 16x16x32, 128x128 tile, 4 waves.
// ---------------------------------------------------------------------------
__global__ __launch_bounds__(256) void logits_kernel(
    const unsigned short* __restrict__ hs, const unsigned short* __restrict__ Wlt,
    const float* __restrict__ bl, float* __restrict__ out)
{
  __shared__ unsigned short As[128][40];
  __shared__ unsigned short Bs[128][40];
  const int tid = threadIdx.x;
  const int bx = blockIdx.x, by = blockIdx.y;
  const int lane = tid & 63, w = tid >> 6;
  const int wr = w >> 1, wc = w & 1;

  f32x4 acc[4][4];
  #pragma unroll
  for (int i = 0; i < 4; i++) {
    #pragma unroll
    for (int j = 0; j < 4; j++) acc[i][j] = (f32x4){0.0f, 0.0f, 0.0f, 0.0f};
  }

  for (int kk = 0; kk < 512; kk += 32) {
    #pragma unroll
    for (int i = 0; i < 2; i++) {
      int chunk = tid * 2 + i;
      int r = chunk >> 2, c8 = (chunk & 3) * 8;
      *(uint4*)&As[r][c8] = *(const uint4*)&hs[(size_t)(by * 128 + r) * 512 + kk + c8];
      *(uint4*)&Bs[r][c8] = *(const uint4*)&Wlt[(size_t)(bx * 128 + r) * 512 + kk + c8];
    }
    __syncthreads();
    short8 af[4], bf[4];
    #pragma unroll
    for (int fr = 0; fr < 4; fr++)
      af[fr] = *(const short8*)&As[wr * 64 + fr * 16 + (lane & 15)][(lane >> 4) * 8];
    #pragma unroll
    for (int fc = 0; fc < 4; fc++)
      bf[fc] = *(const short8*)&Bs[wc * 64 + fc * 16 + (lane & 15)][(lane >> 4) * 8];
    #pragma unroll
    for (int fr = 0; fr < 4; fr++) {
      #pragma unroll
      for (int fc = 0; fc < 4; fc++)
        acc[fr][fc] = __builtin_amdgcn_mfma_f32_16x16x32_bf16(af[fr], bf[fc], acc[fr][fc], 0, 0, 0);
    }
    __syncthreads();
  }

  #pragma unroll
  for (int fc = 0; fc < 4; fc++) {
    int col = bx * 128 + wc * 64 + fc * 16 + (lane & 15);
    float blv = bl[col];
    #pragma unroll
    for (int fr = 0; fr < 4; fr++) {
      int row0 = by * 128 + wr * 64 + fr * 16 + (lane >> 4) * 4;
      #pragma unroll
      for (int j = 0; j < 4; j++) {
        int row = row0 + j;
        int orow = (row & 255) * 8 + (row >> 8);
        out[(size_t)orow * VOCAB + col] = acc[fr][fc][j] + blv;
      }
    }
  }
}

// ---------------------------------------------------------------------------
extern "C" void kernel_launch(void* const* d_in, const int* in_sizes, int n_in,
                              void* d_out, int out_size, void* d_ws, size_t ws_size,
                              hipStream_t stream)
{
  const float* ctx = (const float*)d_in[0];
  const float* Wm  = (const float*)d_in[1];
  const float* bm  = (const float*)d_in[2];
  const float* W   = (const float*)d_in[3];
  const float* U   = (const float*)d_in[4];
  const float* b   = (const float*)d_in[5];
  const float* Wl  = (const float*)d_in[6];
  const float* bl  = (const float*)d_in[7];
  float* out = (float*)d_out;

  char* ws = (char*)d_ws;
  uint64_t* hb        = (uint64_t*)ws;                                   // 8 KB (2x512 u64)
  float* xz           = (float*)(ws + 65536);                            // 2 MB
  unsigned short* hs  = (unsigned short*)(ws + 65536 + (1 << 21));       // 2 MB
  unsigned* Up        = (unsigned*)(ws + 65536 + (2 << 21));             // 2 MB
  unsigned short* Wlt = (unsigned short*)(ws + 65536 + (3 << 21));       // 32.77 MB

  hipMemsetAsync(hb, 0, 8192, stream);  // h_0 = 0 with tag 0 (both parities)
  prep_kernel<<<dim3(64), dim3(512), 0, stream>>>(ctx, Wm, bm, W, b, xz);
  uconv_kernel<<<dim3(256), dim3(256), 0, stream>>>(U, Up);
  wl_convert_kernel<<<dim3(125), dim3(256), 0, stream>>>(Wl, Wlt);

  void* args[] = { (void*)&xz, (void*)&Up, (void*)&hb, (void*)&hs };
  hipLaunchCooperativeKernel((void*)lstm_kernel, dim3(NWG), dim3(512), args, 0, stream);

  logits_kernel<<<dim3(250, 16), dim3(256), 0, stream>>>(hs, Wlt, bl, out);
}

// Round 7
// 4979.589 us; speedup vs baseline: 1.2416x; 1.0261x over previous
//
#include <hip/hip_runtime.h>
#include <stdint.h>

#define D 512
#define T 2048      // S * var_num = 8 * 256
#define VOCAB 32000
#define NWG 16      // LSTM workgroups

typedef __attribute__((ext_vector_type(8))) short short8;
typedef __attribute__((ext_vector_type(4))) float f32x4;
typedef __attribute__((ext_vector_type(8))) unsigned short u16x8;
typedef __attribute__((ext_vector_type(2))) __fp16 f16x2;   // matches cvt_pkrtz return

__device__ __forceinline__ float fast_rcp(float x) { return __builtin_amdgcn_rcpf(x); }
__device__ __forceinline__ float sigm(float x) { return fast_rcp(1.0f + __expf(-x)); }
__device__ __forceinline__ float tanh_fast(float x) {
  float e = __expf(2.0f * x);
  return 1.0f - 2.0f * fast_rcp(e + 1.0f);  // saturates correctly at +-1, no NaN
}
__device__ __forceinline__ unsigned short f2bf(float f) {  // RTNE float->bf16
  unsigned u = __float_as_uint(f);
  unsigned r = u + 0x7fffu + ((u >> 16) & 1u);
  return (unsigned short)(r >> 16);
}
__device__ __forceinline__ uint64_t AL(const uint64_t* p) {
  return __hip_atomic_load(p, __ATOMIC_RELAXED, __HIP_MEMORY_SCOPE_AGENT);
}
union U32H2 { unsigned u; f16x2 h; };

// ---------------------------------------------------------------------------
// Kernel 1: merged = ctx @ Wm + bm ; xz = merged @ W + b   (per 4-row block)
// ---------------------------------------------------------------------------
__global__ __launch_bounds__(512) void prep_kernel(
    const float* __restrict__ ctx, const float* __restrict__ Wm,
    const float* __restrict__ bm, const float* __restrict__ W,
    const float* __restrict__ b, float* __restrict__ xz)
{
  __shared__ float ctx_s[4][1024];
  __shared__ float mg_s[4][512];
  const int tid = threadIdx.x;
  const int r0 = blockIdx.x * 4;

  for (int i = tid; i < 1024; i += 512) {
    int rr = i >> 8, c4 = (i & 255) * 4;
    *(float4*)&ctx_s[rr][c4] = *(const float4*)&ctx[(size_t)(r0 + rr) * 1024 + c4];
  }
  __syncthreads();
  {
    const int rr = tid >> 7, cg = (tid & 127) * 4;
    float a0 = bm[cg], a1 = bm[cg + 1], a2 = bm[cg + 2], a3 = bm[cg + 3];
    for (int k = 0; k < 1024; k += 4) {
      float4 cv = *(float4*)&ctx_s[rr][k];
      #pragma unroll
      for (int kk = 0; kk < 4; kk++) {
        float cc = (kk == 0) ? cv.x : (kk == 1) ? cv.y : (kk == 2) ? cv.z : cv.w;
        float4 wv = *(const float4*)&Wm[(size_t)(k + kk) * 512 + cg];
        a0 += cc * wv.x; a1 += cc * wv.y; a2 += cc * wv.z; a3 += cc * wv.w;
      }
    }
    *(float4*)&mg_s[rr][cg] = make_float4(a0, a1, a2, a3);
  }
  __syncthreads();
  {
    const int rr = tid >> 7, cg = (tid & 127) * 16;
    float acc[16];
    #pragma unroll
    for (int c = 0; c < 16; c++) acc[c] = b[cg + c];
    for (int k = 0; k < 512; k += 4) {
      float4 mv = *(float4*)&mg_s[rr][k];
      #pragma unroll
      for (int kk = 0; kk < 4; kk++) {
        float cc = (kk == 0) ? mv.x : (kk == 1) ? mv.y : (kk == 2) ? mv.z : mv.w;
        #pragma unroll
        for (int c4 = 0; c4 < 4; c4++) {
          float4 wv = *(const float4*)&W[(size_t)(k + kk) * 2048 + cg + c4 * 4];
          acc[c4 * 4 + 0] += cc * wv.x; acc[c4 * 4 + 1] += cc * wv.y;
          acc[c4 * 4 + 2] += cc * wv.z; acc[c4 * 4 + 3] += cc * wv.w;
        }
      }
    }
    #pragma unroll
    for (int c4 = 0; c4 < 4; c4++)
      *(float4*)&xz[(size_t)(r0 + rr) * 2048 + cg + c4 * 4] =
          make_float4(acc[c4 * 4], acc[c4 * 4 + 1], acc[c4 * 4 + 2], acc[c4 * 4 + 3]);
  }
}

// ---------------------------------------------------------------------------
// Kernel 2: Wlt[c][k] = bf16(Wl[k][c])
// ---------------------------------------------------------------------------
__global__ __launch_bounds__(256) void wl_convert_kernel(
    const float* __restrict__ Wl, unsigned short* __restrict__ Wlt)
{
  const int c = blockIdx.x * 256 + threadIdx.x;
  for (int k8 = 0; k8 < 64; k8++) {
    u16x8 v;
    #pragma unroll
    for (int e = 0; e < 8; e++)
      v[e] = f2bf(Wl[(size_t)(k8 * 8 + e) * VOCAB + c]);
    *(u16x8*)&Wlt[(size_t)c * 512 + k8 * 8] = v;
  }
}

// ---------------------------------------------------------------------------
// Kernel 2b: Up[p][c] = pack_f16( U[(p>>5)*64 + (p&31)][c],
//                                 U[(p>>5)*64 + (p&31) + 32][c] )
// ---------------------------------------------------------------------------
__global__ __launch_bounds__(256) void uconv_kernel(
    const float* __restrict__ U, unsigned* __restrict__ Up)
{
  const int p = blockIdx.x;              // 0..255
  const int c0 = threadIdx.x * 8;        // 8 cols per thread
  const int r_lo = (p >> 5) * 64 + (p & 31);
  const float* lo = &U[(size_t)r_lo * 2048 + c0];
  const float* hi = &U[(size_t)(r_lo + 32) * 2048 + c0];
  unsigned outv[8];
  #pragma unroll
  for (int c = 0; c < 8; c++) {
    U32H2 w;
    w.h[0] = (__fp16)lo[c];
    w.h[1] = (__fp16)hi[c];
    outv[c] = w.u;
  }
  #pragma unroll
  for (int c4 = 0; c4 < 2; c4++)
    *(uint4*)&Up[(size_t)p * 2048 + c0 + c4 * 4] =
        make_uint4(outv[c4 * 4], outv[c4 * 4 + 1], outv[c4 * 4 + 2], outv[c4 * 4 + 3]);
}

// ---------------------------------------------------------------------------
// Kernel 3: sequential LSTM over T steps. 16 WGs x 512 threads (cooperative).
// Same structure as R6, ONE decisive change: explicit occupancy attributes
//   amdgpu_flat_work_group_size(512,512) + amdgpu_waves_per_eu(2,2)
// => VGPR budget 256/wave. R2/R4 (launch_bounds) let the allocator target
// ~10 waves/EU (budget ~52): with remat illegal (volatile loads) it SPILLED
// u2 to scratch and re-read 256B/thread/step (R6: VGPR=52, 2.21us/step).
// With budget 256, keeping the 64 u2 words resident beats spilling.
// Verification signal: VGPR_Count >= 100.
// ---------------------------------------------------------------------------
__global__
__attribute__((amdgpu_flat_work_group_size(512, 512)))
__attribute__((amdgpu_waves_per_eu(2, 2)))
void lstm_kernel(
    const float* __restrict__ xz, const unsigned* __restrict__ Up,
    uint64_t* __restrict__ hb, unsigned short* __restrict__ hs)
{
  __shared__ float h_lds[512];
  __shared__ float z_lds[128];
  const int tid = threadIdx.x;
  const int wg = blockIdx.x;
  const int rb = tid & 31;
  const int cb = tid >> 5;
  const int gate = cb >> 2;
  const int gcol0 = gate * 512 + wg * 32 + (cb & 3) * 8;

  // one-time exactly-once U load: 8 pairs x 8 cols = 16x dwordx4
  uint4 uv[16];
  #pragma unroll
  for (int ep = 0; ep < 8; ep++) {
    const unsigned* ap = &Up[(size_t)(ep * 32 + rb) * 2048 + gcol0];
    asm volatile("global_load_dwordx4 %0, %1, off"
                 : "=v"(uv[ep * 2]) : "v"(ap));
    asm volatile("global_load_dwordx4 %0, %1, off offset:16"
                 : "=v"(uv[ep * 2 + 1]) : "v"(ap));
  }
  asm volatile("s_waitcnt vmcnt(0)" ::: "memory");
  unsigned u2[8][8];
  #pragma unroll
  for (int ep = 0; ep < 8; ep++) {
    uint4 a = uv[ep * 2], b4 = uv[ep * 2 + 1];
    u2[ep][0] = a.x; u2[ep][1] = a.y; u2[ep][2] = a.z; u2[ep][3] = a.w;
    u2[ep][4] = b4.x; u2[ep][5] = b4.y; u2[ep][6] = b4.z; u2[ep][7] = b4.w;
  }

  float creg = 0.0f;

  for (int t = 0; t < T; t++) {
    // keep the 64 packed-U words live across the backedge (no instructions)
    #pragma unroll
    for (int ep = 0; ep < 8; ep++) {
      #pragma unroll
      for (int c = 0; c < 8; c++) asm volatile("" : "+v"(u2[ep][c]));
    }
    float xzv0, xzv1, xzv2, xzv3;
    if (tid < 32) {  // prefetch this step's xz (independent of h)
      const float* xp = &xz[(size_t)(t & 255) * 2048 + wg * 32 + tid];
      xzv0 = xp[0]; xzv1 = xp[512]; xzv2 = xp[1024]; xzv3 = xp[1536];
    }
    // poll ONE word: unit `tid` of h_t
    {
      const uint64_t* hw = hb + (size_t)((t & 1) << 9) + tid;
      uint64_t wv;
      for (;;) {
        wv = AL(hw);
        if ((unsigned)(wv >> 32) == (unsigned)t) break;
      }
      h_lds[tid] = __uint_as_float((unsigned)wv);
    }
    __syncthreads();  // A: h_lds complete

    float zp[8];
    #pragma unroll
    for (int c = 0; c < 8; c++) zp[c] = 0.0f;
    #pragma unroll
    for (int ep = 0; ep < 8; ep++) {
      float hlo = h_lds[rb + 64 * ep];        // bank rb, 2-lane broadcast
      float hhi = h_lds[rb + 64 * ep + 32];   // bank rb
      f16x2 h2 = __builtin_amdgcn_cvt_pkrtz(hlo, hhi);
      #pragma unroll
      for (int c = 0; c < 8; c++) {
        U32H2 w; w.u = u2[ep][c];
        zp[c] = __builtin_amdgcn_fdot2(h2, w.h, zp[c], false);
      }
    }
    // reduce over the 32 threads sharing cb (xor masks stay in 32-lane group)
    #pragma unroll
    for (int m = 1; m < 32; m <<= 1) {
      #pragma unroll
      for (int c = 0; c < 8; c++) zp[c] += __shfl_xor(zp[c], m, 64);
    }
    if (rb == 0) {
      *(float4*)&z_lds[cb * 8]     = make_float4(zp[0], zp[1], zp[2], zp[3]);
      *(float4*)&z_lds[cb * 8 + 4] = make_float4(zp[4], zp[5], zp[6], zp[7]);
    }
    __syncthreads();  // B: z_lds complete (also orders h_lds reads vs next write)
    if (tid < 32) {   // gates for unit u = tid
      float zi = z_lds[tid]       + xzv0;
      float zf = z_lds[32 + tid]  + xzv1;
      float zg = z_lds[64 + tid]  + xzv2;
      float zo = z_lds[96 + tid]  + xzv3;
      float ig = sigm(zi), fg = sigm(zf), gg = tanh_fast(zg), og = sigm(zo);
      creg = fg * creg + ig * gg;
      float h = og * tanh_fast(creg);
      // critical store FIRST (other WGs poll it), bookkeeping after
      uint64_t pk = ((uint64_t)(unsigned)(t + 1) << 32) | (uint64_t)__float_as_uint(h);
      __hip_atomic_store(&hb[(size_t)(((t + 1) & 1) << 9) + wg * 32 + tid], pk,
                         __ATOMIC_RELAXED, __HIP_MEMORY_SCOPE_AGENT);
      hs[(size_t)t * 512 + wg * 32 + tid] = f2bf(h);
    }
  }
}

// ---------------------------------------------------------------------------
// Kernel 4: logits = hs @ Wl + bl, bf16 MFMA 16x16x32, 128x128 tile, 4 waves.
// ---------------------------------------------------------------------------
__global__ __launch_bounds__(256) void logits_kernel(
    const unsigned short* __restrict__ hs, const unsigned short* __restrict__ Wlt,
    const float* __restrict__ bl, float* __restrict__ out)
{
  __shared__ unsigned short As[128][40];
  __shared__ unsigned short Bs[128][40];
  const int tid = threadIdx.x;
  const int bx = blockIdx.x, by = blockIdx.y;
  const int lane = tid & 63, w = tid >> 6;
  const int wr = w >> 1, wc = w & 1;

  f32x4 acc[4][4];
  #pragma unroll
  for (int i = 0; i < 4; i++) {
    #pragma unroll
    for (int j = 0; j < 4; j++) acc[i][j] = (f32x4){0.0f, 0.0f, 0.0f, 0.0f};
  }

  for (int kk = 0; kk < 512; kk += 32) {
    #pragma unroll
    for (int i = 0; i < 2; i++) {
      int chunk = tid * 2 + i;
      int r = chunk >> 2, c8 = (chunk & 3) * 8;
      *(uint4*)&As[r][c8] = *(const uint4*)&hs[(size_t)(by * 128 + r) * 512 + kk + c8];
      *(uint4*)&Bs[r][c8] = *(const uint4*)&Wlt[(size_t)(bx * 128 + r) * 512 + kk + c8];
    }
    __syncthreads();
    short8 af[4], bf[4];
    #pragma unroll
    for (int fr = 0; fr < 4; fr++)
      af[fr] = *(const short8*)&As[wr * 64 + fr * 16 + (lane & 15)][(lane >> 4) * 8];
    #pragma unroll
    for (int fc = 0; fc < 4; fc++)
      bf[fc] = *(const short8*)&Bs[wc * 64 + fc * 16 + (lane & 15)][(lane >> 4) * 8];
    #pragma unroll
    for (int fr = 0; fr < 4; fr++) {
      #pragma unroll
      for (int fc = 0; fc < 4; fc++)
        acc[fr][fc] = __builtin_amdgcn_mfma_f32_16x16x32_bf16(af[fr], bf[fc], acc[fr][fc], 0, 0, 0);
    }
    __syncthreads();
  }

  #pragma unroll
  for (int fc = 0; fc < 4; fc++) {
    int col = bx * 128 + wc * 64 + fc * 16 + (lane & 15);
    float blv = bl[col];
    #pragma unroll
    for (int fr = 0; fr < 4; fr++) {
      int row0 = by * 128 + wr * 64 + fr * 16 + (lane >> 4) * 4;
      #pragma unroll
      for (int j = 0; j < 4; j++) {
        int row = row0 + j;
        int orow = (row & 255) * 8 + (row >> 8);
        out[(size_t)orow * VOCAB + col] = acc[fr][fc][j] + blv;
      }
    }
  }
}

// ---------------------------------------------------------------------------
extern "C" void kernel_launch(void* const* d_in, const int* in_sizes, int n_in,
                              void* d_out, int out_size, void* d_ws, size_t ws_size,
                              hipStream_t stream)
{
  const float* ctx = (const float*)d_in[0];
  const float* Wm  = (const float*)d_in[1];
  const float* bm  = (const float*)d_in[2];
  const float* W   = (const float*)d_in[3];
  const float* U   = (const float*)d_in[4];
  const float* b   = (const float*)d_in[5];
  const float* Wl  = (const float*)d_in[6];
  const float* bl  = (const float*)d_in[7];
  float* out = (float*)d_out;

  char* ws = (char*)d_ws;
  uint64_t* hb        = (uint64_t*)ws;                                   // 8 KB (2x512 u64)
  float* xz           = (float*)(ws + 65536);                            // 2 MB
  unsigned short* hs  = (unsigned short*)(ws + 65536 + (1 << 21));       // 2 MB
  unsigned* Up        = (unsigned*)(ws + 65536 + (2 << 21));             // 2 MB
  unsigned short* Wlt = (unsigned short*)(ws + 65536 + (3 << 21));       // 32.77 MB

  hipMemsetAsync(hb, 0, 8192, stream);  // h_0 = 0 with tag 0 (both parities)
  prep_kernel<<<dim3(64), dim3(512), 0, stream>>>(ctx, Wm, bm, W, b, xz);
  uconv_kernel<<<dim3(256), dim3(256), 0, stream>>>(U, Up);
  wl_convert_kernel<<<dim3(125), dim3(256), 0, stream>>>(Wl, Wlt);

  void* args[] = { (void*)&xz, (void*)&Up, (void*)&hb, (void*)&hs };
  hipLaunchCooperativeKernel((void*)lstm_kernel, dim3(NWG), dim3(512), args, 0, stream);

  logits_kernel<<<dim3(250, 16), dim3(256), 0, stream>>>(hs, Wlt, bl, out);
}

// Round 9
// 4784.044 us; speedup vs baseline: 1.2923x; 1.0409x over previous
//
#include <hip/hip_runtime.h>
#include <stdint.h>

#define D 512
#define T 2048      // S * var_num = 8 * 256
#define VOCAB 32000
#define NWG 16      // LSTM workgroups

typedef __attribute__((ext_vector_type(8))) short short8;
typedef __attribute__((ext_vector_type(4))) float f32x4;
typedef __attribute__((ext_vector_type(8))) unsigned short u16x8;
typedef __attribute__((ext_vector_type(2))) __fp16 f16x2;   // matches cvt_pkrtz return

__device__ __forceinline__ float fast_rcp(float x) { return __builtin_amdgcn_rcpf(x); }
__device__ __forceinline__ float sigm(float x) { return fast_rcp(1.0f + __expf(-x)); }
__device__ __forceinline__ float tanh_fast(float x) {
  float e = __expf(2.0f * x);
  return 1.0f - 2.0f * fast_rcp(e + 1.0f);  // saturates correctly at +-1, no NaN
}
__device__ __forceinline__ unsigned short f2bf(float f) {  // RTNE float->bf16
  unsigned u = __float_as_uint(f);
  unsigned r = u + 0x7fffu + ((u >> 16) & 1u);
  return (unsigned short)(r >> 16);
}
__device__ __forceinline__ uint64_t AL(const uint64_t* p) {
  return __hip_atomic_load(p, __ATOMIC_RELAXED, __HIP_MEMORY_SCOPE_AGENT);
}
union U32H2 { unsigned u; f16x2 h; };

// ---------------------------------------------------------------------------
// Kernel 1: merged = ctx @ Wm + bm ; xz = merged @ W + b   (per 4-row block)
// ---------------------------------------------------------------------------
__global__ __launch_bounds__(512) void prep_kernel(
    const float* __restrict__ ctx, const float* __restrict__ Wm,
    const float* __restrict__ bm, const float* __restrict__ W,
    const float* __restrict__ b, float* __restrict__ xz)
{
  __shared__ float ctx_s[4][1024];
  __shared__ float mg_s[4][512];
  const int tid = threadIdx.x;
  const int r0 = blockIdx.x * 4;

  for (int i = tid; i < 1024; i += 512) {
    int rr = i >> 8, c4 = (i & 255) * 4;
    *(float4*)&ctx_s[rr][c4] = *(const float4*)&ctx[(size_t)(r0 + rr) * 1024 + c4];
  }
  __syncthreads();
  {
    const int rr = tid >> 7, cg = (tid & 127) * 4;
    float a0 = bm[cg], a1 = bm[cg + 1], a2 = bm[cg + 2], a3 = bm[cg + 3];
    for (int k = 0; k < 1024; k += 4) {
      float4 cv = *(float4*)&ctx_s[rr][k];
      #pragma unroll
      for (int kk = 0; kk < 4; kk++) {
        float cc = (kk == 0) ? cv.x : (kk == 1) ? cv.y : (kk == 2) ? cv.z : cv.w;
        float4 wv = *(const float4*)&Wm[(size_t)(k + kk) * 512 + cg];
        a0 += cc * wv.x; a1 += cc * wv.y; a2 += cc * wv.z; a3 += cc * wv.w;
      }
    }
    *(float4*)&mg_s[rr][cg] = make_float4(a0, a1, a2, a3);
  }
  __syncthreads();
  {
    const int rr = tid >> 7, cg = (tid & 127) * 16;
    float acc[16];
    #pragma unroll
    for (int c = 0; c < 16; c++) acc[c] = b[cg + c];
    for (int k = 0; k < 512; k += 4) {
      float4 mv = *(float4*)&mg_s[rr][k];
      #pragma unroll
      for (int kk = 0; kk < 4; kk++) {
        float cc = (kk == 0) ? mv.x : (kk == 1) ? mv.y : (kk == 2) ? mv.z : mv.w;
        #pragma unroll
        for (int c4 = 0; c4 < 4; c4++) {
          float4 wv = *(const float4*)&W[(size_t)(k + kk) * 2048 + cg + c4 * 4];
          acc[c4 * 4 + 0] += cc * wv.x; acc[c4 * 4 + 1] += cc * wv.y;
          acc[c4 * 4 + 2] += cc * wv.z; acc[c4 * 4 + 3] += cc * wv.w;
        }
      }
    }
    #pragma unroll
    for (int c4 = 0; c4 < 4; c4++)
      *(float4*)&xz[(size_t)(r0 + rr) * 2048 + cg + c4 * 4] =
          make_float4(acc[c4 * 4], acc[c4 * 4 + 1], acc[c4 * 4 + 2], acc[c4 * 4 + 3]);
  }
}

// ---------------------------------------------------------------------------
// Kernel 2: Wlt[c][k] = bf16(Wl[k][c])
// ---------------------------------------------------------------------------
__global__ __launch_bounds__(256) void wl_convert_kernel(
    const float* __restrict__ Wl, unsigned short* __restrict__ Wlt)
{
  const int c = blockIdx.x * 256 + threadIdx.x;
  for (int k8 = 0; k8 < 64; k8++) {
    u16x8 v;
    #pragma unroll
    for (int e = 0; e < 8; e++)
      v[e] = f2bf(Wl[(size_t)(k8 * 8 + e) * VOCAB + c]);
    *(u16x8*)&Wlt[(size_t)c * 512 + k8 * 8] = v;
  }
}

// ---------------------------------------------------------------------------
// Kernel 2b: per-thread-contiguous packed-f16 U for unit-major lstm mapping.
// lstm thread (wg, tid=cb*32+rb) owns cols col(c) = (c>>1)*512 + wg*32+cb*2 +
// (c&1), c=0..7 (4 gates x 2 units), rows pairs {rb+64ep, rb+64ep+32}.
// Upr[(wg*512+tid)*64 + ep*8 + c] = pack_f16(U[rb+64ep][col], U[rb+64ep+32][col])
// -> lstm loads 16 contiguous dwordx4 per thread (R3's scattered-load fix).
// ---------------------------------------------------------------------------
__global__ __launch_bounds__(256) void uconv2_kernel(
    const float* __restrict__ U, unsigned* __restrict__ Upr)
{
  const int blk = blockIdx.x;           // wg*16 + cb
  const int wg = blk >> 4, cb = blk & 15;
  const int rb = threadIdx.x & 31, ep = threadIdx.x >> 5;
  const int u0 = wg * 32 + cb * 2;
  const int r = rb + 64 * ep;
  unsigned outv[8];
  #pragma unroll
  for (int g = 0; g < 4; g++) {
    float2 lo = *(const float2*)&U[(size_t)r * 2048 + g * 512 + u0];
    float2 hi = *(const float2*)&U[(size_t)(r + 32) * 2048 + g * 512 + u0];
    U32H2 w0; w0.h[0] = (__fp16)lo.x; w0.h[1] = (__fp16)hi.x;
    U32H2 w1; w1.h[0] = (__fp16)lo.y; w1.h[1] = (__fp16)hi.y;
    outv[g * 2] = w0.u; outv[g * 2 + 1] = w1.u;
  }
  unsigned* dst = Upr + ((size_t)(wg * 512 + cb * 32 + rb)) * 64 + ep * 8;
  *(uint4*)dst = make_uint4(outv[0], outv[1], outv[2], outv[3]);
  *(uint4*)(dst + 4) = make_uint4(outv[4], outv[5], outv[6], outv[7]);
}

// ---------------------------------------------------------------------------
// Kernel 3: sequential LSTM, 16 WGs x 512 (cooperative). Unit-major mapping:
// group cb owns units u0=wg*32+cb*2, u0+1 (4 gates each). ONE barrier/step
// (parity-buffered h_lds), no z_lds. Split-butterfly reduce (9 shuffles).
// Gate lanes rb in {0,1} compute 1 unit each and publish immediately.
// Exchange: agent-scope tagged u64 words (proven R2-R7); only tid<128 poll
// (4 words each); own-WG words go through LDS, never MALL.
// ---------------------------------------------------------------------------
__global__
__attribute__((amdgpu_flat_work_group_size(512, 512)))
__attribute__((amdgpu_waves_per_eu(2, 2)))
void lstm_kernel(
    const float* __restrict__ xz, const unsigned* __restrict__ Upr,
    uint64_t* __restrict__ hb, unsigned short* __restrict__ hs)
{
  __shared__ float h_lds[2][512];
  const int tid = threadIdx.x;
  const int wg = blockIdx.x;
  const int rb = tid & 31;
  const int lane = tid & 63;
  const int cb = tid >> 5;
  const int u0 = wg * 32 + cb * 2;
  const bool gl = (rb < 2);                               // gate lane: unit u0+rb
  const bool mypoll = (tid < 128) && ((tid >> 3) != wg);  // skip own-WG words

  // one-time exactly-once U load: 16 contiguous dwordx4 (volatile: cannot be
  // re-executed -> no per-step reload; attrs give 256-VGPR budget -> no spill)
  const unsigned* ubase = Upr + ((size_t)(wg * 512 + tid)) * 64;
  uint4 uv[16];
  #pragma unroll
  for (int i = 0; i < 16; i++) {
    const unsigned* ap = ubase + i * 4;
    asm volatile("global_load_dwordx4 %0, %1, off" : "=v"(uv[i]) : "v"(ap));
  }
  asm volatile("s_waitcnt vmcnt(0)" ::: "memory");
  unsigned u2[8][8];
  #pragma unroll
  for (int ep = 0; ep < 8; ep++) {
    uint4 a = uv[ep * 2], b4 = uv[ep * 2 + 1];
    u2[ep][0] = a.x; u2[ep][1] = a.y; u2[ep][2] = a.z; u2[ep][3] = a.w;
    u2[ep][4] = b4.x; u2[ep][5] = b4.y; u2[ep][6] = b4.z; u2[ep][7] = b4.w;
  }

  h_lds[0][tid] = 0.0f;   // h_0 = 0 (own-range needed; rest benign)
  float creg = 0.0f;
  const int b0 = rb & 1, b1 = (rb >> 1) & 1, b2v = (rb >> 2) & 1;

  for (int t = 0; t < T; t++) {
    #pragma unroll
    for (int ep = 0; ep < 8; ep++) {
      #pragma unroll
      for (int c = 0; c < 8; c++) asm volatile("" : "+v"(u2[ep][c]));  // pin
    }
    float xv0, xv1, xv2, xv3;
    if (gl) {  // xz for this unit's 4 gates (independent of h; hides in poll)
      const float* xp = &xz[(size_t)(t & 255) * 2048 + u0 + rb];
      xv0 = xp[0]; xv1 = xp[512]; xv2 = xp[1024]; xv3 = xp[1536];
    }
    const int par = t & 1;
    if (mypoll) {  // poll 4 consecutive words (batched loads, all in flight)
      uint64_t* hw = hb + ((size_t)par << 9) + tid * 4;
      const unsigned tt = (unsigned)t;
      for (;;) {
        uint64_t w0 = AL(hw), w1 = AL(hw + 1), w2 = AL(hw + 2), w3 = AL(hw + 3);
        if (((unsigned)(w0 >> 32) == tt) & ((unsigned)(w1 >> 32) == tt) &
            ((unsigned)(w2 >> 32) == tt) & ((unsigned)(w3 >> 32) == tt)) {
          h_lds[par][tid * 4 + 0] = __uint_as_float((unsigned)w0);
          h_lds[par][tid * 4 + 1] = __uint_as_float((unsigned)w1);
          h_lds[par][tid * 4 + 2] = __uint_as_float((unsigned)w2);
          h_lds[par][tid * 4 + 3] = __uint_as_float((unsigned)w3);
          break;
        }
      }
    }
    __syncthreads();  // h_lds[par] complete

    // matvec: rows {rb+64ep, rb+64ep+32} x 8 cols, packed-f16 dot2
    float zp[8];
    #pragma unroll
    for (int c = 0; c < 8; c++) zp[c] = 0.0f;
    #pragma unroll
    for (int ep = 0; ep < 8; ep++) {
      float hlo = h_lds[par][rb + 64 * ep];
      float hhi = h_lds[par][rb + 64 * ep + 32];
      f16x2 h2 = __builtin_amdgcn_cvt_pkrtz(hlo, hhi);
      #pragma unroll
      for (int c = 0; c < 8; c++) {
        U32H2 w; w.u = u2[ep][c];
        zp[c] = __builtin_amdgcn_fdot2(h2, w.h, zp[c], false);
      }
    }
    // split-butterfly reduce: after L1-L3 lane holds value c = rb&7 (partial
    // over its 8-lane subgroup), L4+L5 complete the 32-lane sum. 9 shuffles.
    float q[4];
    #pragma unroll
    for (int j = 0; j < 4; j++) {
      float send = b0 ? zp[2 * j] : zp[2 * j + 1];
      float recv = __shfl_xor(send, 1, 64);
      q[j] = (b0 ? zp[2 * j + 1] : zp[2 * j]) + recv;
    }
    float r2[2];
    #pragma unroll
    for (int j = 0; j < 2; j++) {
      float send = b1 ? q[2 * j] : q[2 * j + 1];
      float recv = __shfl_xor(send, 2, 64);
      r2[j] = (b1 ? q[2 * j + 1] : q[2 * j]) + recv;
    }
    float z;
    {
      float send = b2v ? r2[0] : r2[1];
      float recv = __shfl_xor(send, 4, 64);
      z = (b2v ? r2[1] : r2[0]) + recv;
    }
    z += __shfl_xor(z, 8, 64);
    z += __shfl_xor(z, 16, 64);
    // redistribute: gate lane (rb<2) needs c = {rb, 2+rb, 4+rb, 6+rb}
    float zf = __shfl(z, (lane & 32) + 2 + b0, 64);
    float zg = __shfl(z, (lane & 32) + 4 + b0, 64);
    float zo = __shfl(z, (lane & 32) + 6 + b0, 64);

    if (gl) {  // gates for unit u0+rb
      float ig = sigm(z + xv0);
      float fg = sigm(zf + xv1);
      float gg = tanh_fast(zg + xv2);
      float og = sigm(zo + xv3);
      creg = fg * creg + ig * gg;
      float h = og * tanh_fast(creg);
      uint64_t pk = ((uint64_t)(unsigned)(t + 1) << 32) | (uint64_t)__float_as_uint(h);
      __hip_atomic_store(&hb[((size_t)((t + 1) & 1) << 9) + u0 + rb], pk,
                         __ATOMIC_RELAXED, __HIP_MEMORY_SCOPE_AGENT);
      h_lds[(t + 1) & 1][u0 + rb] = h;   // own-WG shortcut (pollers skip these)
      hs[(size_t)t * 512 + u0 + rb] = f2bf(h);
    }
  }
}

// ---------------------------------------------------------------------------
// Kernel 4: logits = hs @ Wl + bl, bf16 MFMA 16x16x32, 128x128 tile, 4 waves.
// ---------------------------------------------------------------------------
__global__ __launch_bounds__(256) void logits_kernel(
    const unsigned short* __restrict__ hs, const unsigned short* __restrict__ Wlt,
    const float* __restrict__ bl, float* __restrict__ out)
{
  __shared__ unsigned short As[128][40];
  __shared__ unsigned short Bs[128][40];
  const int tid = threadIdx.x;
  const int bx = blockIdx.x, by = blockIdx.y;
  const int lane = tid & 63, w = tid >> 6;
  const int wr = w >> 1, wc = w & 1;

  f32x4 acc[4][4];
  #pragma unroll
  for (int i = 0; i < 4; i++) {
    #pragma unroll
    for (int j = 0; j < 4; j++) acc[i][j] = (f32x4){0.0f, 0.0f, 0.0f, 0.0f};
  }

  for (int kk = 0; kk < 512; kk += 32) {
    #pragma unroll
    for (int i = 0; i < 2; i++) {
      int chunk = tid * 2 + i;
      int r = chunk >> 2, c8 = (chunk & 3) * 8;
      *(uint4*)&As[r][c8] = *(const uint4*)&hs[(size_t)(by * 128 + r) * 512 + kk + c8];
      *(uint4*)&Bs[r][c8] = *(const uint4*)&Wlt[(size_t)(bx * 128 + r) * 512 + kk + c8];
    }
    __syncthreads();
    short8 af[4], bf[4];
    #pragma unroll
    for (int fr = 0; fr < 4; fr++)
      af[fr] = *(const short8*)&As[wr * 64 + fr * 16 + (lane & 15)][(lane >> 4) * 8];
    #pragma unroll
    for (int fc = 0; fc < 4; fc++)
      bf[fc] = *(const short8*)&Bs[wc * 64 + fc * 16 + (lane & 15)][(lane >> 4) * 8];
    #pragma unroll
    for (int fr = 0; fr < 4; fr++) {
      #pragma unroll
      for (int fc = 0; fc < 4; fc++)
        acc[fr][fc] = __builtin_amdgcn_mfma_f32_16x16x32_bf16(af[fr], bf[fc], acc[fr][fc], 0, 0, 0);
    }
    __syncthreads();
  }

  #pragma unroll
  for (int fc = 0; fc < 4; fc++) {
    int col = bx * 128 + wc * 64 + fc * 16 + (lane & 15);
    float blv = bl[col];
    #pragma unroll
    for (int fr = 0; fr < 4; fr++) {
      int row0 = by * 128 + wr * 64 + fr * 16 + (lane >> 4) * 4;
      #pragma unroll
      for (int j = 0; j < 4; j++) {
        int row = row0 + j;
        int orow = (row & 255) * 8 + (row >> 8);
        out[(size_t)orow * VOCAB + col] = acc[fr][fc][j] + blv;
      }
    }
  }
}

// ---------------------------------------------------------------------------
extern "C" void kernel_launch(void* const* d_in, const int* in_sizes, int n_in,
                              void* d_out, int out_size, void* d_ws, size_t ws_size,
                              hipStream_t stream)
{
  const float* ctx = (const float*)d_in[0];
  const float* Wm  = (const float*)d_in[1];
  const float* bm  = (const float*)d_in[2];
  const float* W   = (const float*)d_in[3];
  const float* U   = (const float*)d_in[4];
  const float* b   = (const float*)d_in[5];
  const float* Wl  = (const float*)d_in[6];
  const float* bl  = (const float*)d_in[7];
  float* out = (float*)d_out;

  char* ws = (char*)d_ws;
  uint64_t* hb        = (uint64_t*)ws;                                   // 8 KB (2x512 u64)
  float* xz           = (float*)(ws + 65536);                            // 2 MB
  unsigned short* hs  = (unsigned short*)(ws + 65536 + (1 << 21));       // 2 MB
  unsigned* Upr       = (unsigned*)(ws + 65536 + (2 << 21));             // 2 MB
  unsigned short* Wlt = (unsigned short*)(ws + 65536 + (3 << 21));       // 32.77 MB

  hipMemsetAsync(hb, 0, 8192, stream);  // h_0 = 0 with tag 0 (both parities)
  prep_kernel<<<dim3(64), dim3(512), 0, stream>>>(ctx, Wm, bm, W, b, xz);
  uconv2_kernel<<<dim3(256), dim3(256), 0, stream>>>(U, Upr);
  wl_convert_kernel<<<dim3(125), dim3(256), 0, stream>>>(Wl, Wlt);

  void* args[] = { (void*)&xz, (void*)&Upr, (void*)&hb, (void*)&hs };
  hipLaunchCooperativeKernel((void*)lstm_kernel, dim3(NWG), dim3(512), args, 0, stream);

  logits_kernel<<<dim3(250, 16), dim3(256), 0, stream>>>(hs, Wlt, bl, out);
}

// Round 11
// 4758.792 us; speedup vs baseline: 1.2992x; 1.0053x over previous
//
#include <hip/hip_runtime.h>
#include <stdint.h>

#define D 512
#define T 2048      // S * var_num = 8 * 256
#define VOCAB 32000
#define NWG 16      // LSTM workgroups

typedef __attribute__((ext_vector_type(8))) short short8;
typedef __attribute__((ext_vector_type(4))) float f32x4;
typedef __attribute__((ext_vector_type(8))) unsigned short u16x8;
typedef __attribute__((ext_vector_type(2))) __fp16 f16x2;   // matches cvt_pkrtz return

__device__ __forceinline__ float fast_rcp(float x) { return __builtin_amdgcn_rcpf(x); }
__device__ __forceinline__ float sigm(float x) { return fast_rcp(1.0f + __expf(-x)); }
__device__ __forceinline__ float tanh_fast(float x) {
  float e = __expf(2.0f * x);
  return 1.0f - 2.0f * fast_rcp(e + 1.0f);  // saturates correctly at +-1, no NaN
}
__device__ __forceinline__ unsigned short f2bf(float f) {  // RTNE float->bf16
  unsigned u = __float_as_uint(f);
  unsigned r = u + 0x7fffu + ((u >> 16) & 1u);
  return (unsigned short)(r >> 16);
}
__device__ __forceinline__ uint64_t AL(const uint64_t* p) {
  return __hip_atomic_load(p, __ATOMIC_RELAXED, __HIP_MEMORY_SCOPE_AGENT);
}
union U32H2 { unsigned u; f16x2 h; };

// ---------------------------------------------------------------------------
// Kernel 1: merged = ctx @ Wm + bm ; xz = merged @ W + b   (per 4-row block)
// ---------------------------------------------------------------------------
__global__ __launch_bounds__(512) void prep_kernel(
    const float* __restrict__ ctx, const float* __restrict__ Wm,
    const float* __restrict__ bm, const float* __restrict__ W,
    const float* __restrict__ b, float* __restrict__ xz)
{
  __shared__ float ctx_s[4][1024];
  __shared__ float mg_s[4][512];
  const int tid = threadIdx.x;
  const int r0 = blockIdx.x * 4;

  for (int i = tid; i < 1024; i += 512) {
    int rr = i >> 8, c4 = (i & 255) * 4;
    *(float4*)&ctx_s[rr][c4] = *(const float4*)&ctx[(size_t)(r0 + rr) * 1024 + c4];
  }
  __syncthreads();
  {
    const int rr = tid >> 7, cg = (tid & 127) * 4;
    float a0 = bm[cg], a1 = bm[cg + 1], a2 = bm[cg + 2], a3 = bm[cg + 3];
    for (int k = 0; k < 1024; k += 4) {
      float4 cv = *(float4*)&ctx_s[rr][k];
      #pragma unroll
      for (int kk = 0; kk < 4; kk++) {
        float cc = (kk == 0) ? cv.x : (kk == 1) ? cv.y : (kk == 2) ? cv.z : cv.w;
        float4 wv = *(const float4*)&Wm[(size_t)(k + kk) * 512 + cg];
        a0 += cc * wv.x; a1 += cc * wv.y; a2 += cc * wv.z; a3 += cc * wv.w;
      }
    }
    *(float4*)&mg_s[rr][cg] = make_float4(a0, a1, a2, a3);
  }
  __syncthreads();
  {
    const int rr = tid >> 7, cg = (tid & 127) * 16;
    float acc[16];
    #pragma unroll
    for (int c = 0; c < 16; c++) acc[c] = b[cg + c];
    for (int k = 0; k < 512; k += 4) {
      float4 mv = *(float4*)&mg_s[rr][k];
      #pragma unroll
      for (int kk = 0; kk < 4; kk++) {
        float cc = (kk == 0) ? mv.x : (kk == 1) ? mv.y : (kk == 2) ? mv.z : mv.w;
        #pragma unroll
        for (int c4 = 0; c4 < 4; c4++) {
          float4 wv = *(const float4*)&W[(size_t)(k + kk) * 2048 + cg + c4 * 4];
          acc[c4 * 4 + 0] += cc * wv.x; acc[c4 * 4 + 1] += cc * wv.y;
          acc[c4 * 4 + 2] += cc * wv.z; acc[c4 * 4 + 3] += cc * wv.w;
        }
      }
    }
    #pragma unroll
    for (int c4 = 0; c4 < 4; c4++)
      *(float4*)&xz[(size_t)(r0 + rr) * 2048 + cg + c4 * 4] =
          make_float4(acc[c4 * 4], acc[c4 * 4 + 1], acc[c4 * 4 + 2], acc[c4 * 4 + 3]);
  }
}

// ---------------------------------------------------------------------------
// Kernel 2: Wlt[c][k] = bf16(Wl[k][c])
// ---------------------------------------------------------------------------
__global__ __launch_bounds__(256) void wl_convert_kernel(
    const float* __restrict__ Wl, unsigned short* __restrict__ Wlt)
{
  const int c = blockIdx.x * 256 + threadIdx.x;
  for (int k8 = 0; k8 < 64; k8++) {
    u16x8 v;
    #pragma unroll
    for (int e = 0; e < 8; e++)
      v[e] = f2bf(Wl[(size_t)(k8 * 8 + e) * VOCAB + c]);
    *(u16x8*)&Wlt[(size_t)c * 512 + k8 * 8] = v;
  }
}

// ---------------------------------------------------------------------------
// Kernel 2b: per-thread-contiguous packed-f16 U for unit-major lstm mapping.
// ---------------------------------------------------------------------------
__global__ __launch_bounds__(256) void uconv2_kernel(
    const float* __restrict__ U, unsigned* __restrict__ Upr)
{
  const int blk = blockIdx.x;           // wg*16 + cb
  const int wg = blk >> 4, cb = blk & 15;
  const int rb = threadIdx.x & 31, ep = threadIdx.x >> 5;
  const int u0 = wg * 32 + cb * 2;
  const int r = rb + 64 * ep;
  unsigned outv[8];
  #pragma unroll
  for (int g = 0; g < 4; g++) {
    float2 lo = *(const float2*)&U[(size_t)r * 2048 + g * 512 + u0];
    float2 hi = *(const float2*)&U[(size_t)(r + 32) * 2048 + g * 512 + u0];
    U32H2 w0; w0.h[0] = (__fp16)lo.x; w0.h[1] = (__fp16)hi.x;
    U32H2 w1; w1.h[0] = (__fp16)lo.y; w1.h[1] = (__fp16)hi.y;
    outv[g * 2] = w0.u; outv[g * 2 + 1] = w1.u;
  }
  unsigned* dst = Upr + ((size_t)(wg * 512 + cb * 32 + rb)) * 64 + ep * 8;
  *(uint4*)dst = make_uint4(outv[0], outv[1], outv[2], outv[3]);
  *(uint4*)(dst + 4) = make_uint4(outv[4], outv[5], outv[6], outv[7]);
}

// ---------------------------------------------------------------------------
// Kernel 3: sequential LSTM, BYTE-IDENTICAL to R9 (last known-good).
// 16 WGs x 512 (cooperative), unit-major mapping, 1 barrier/step,
// split-butterfly reduce, tid<128 poll, agent-scope tagged u64 exchange.
// ---------------------------------------------------------------------------
__global__
__attribute__((amdgpu_flat_work_group_size(512, 512)))
__attribute__((amdgpu_waves_per_eu(2, 2)))
void lstm_kernel(
    const float* __restrict__ xz, const unsigned* __restrict__ Upr,
    uint64_t* __restrict__ hb, unsigned short* __restrict__ hs)
{
  __shared__ float h_lds[2][512];
  const int tid = threadIdx.x;
  const int wg = blockIdx.x;
  const int rb = tid & 31;
  const int lane = tid & 63;
  const int cb = tid >> 5;
  const int u0 = wg * 32 + cb * 2;
  const bool gl = (rb < 2);                               // gate lane: unit u0+rb
  const bool mypoll = (tid < 128) && ((tid >> 3) != wg);  // skip own-WG words

  // one-time exactly-once U load: 16 contiguous dwordx4
  const unsigned* ubase = Upr + ((size_t)(wg * 512 + tid)) * 64;
  uint4 uv[16];
  #pragma unroll
  for (int i = 0; i < 16; i++) {
    const unsigned* ap = ubase + i * 4;
    asm volatile("global_load_dwordx4 %0, %1, off" : "=v"(uv[i]) : "v"(ap));
  }
  asm volatile("s_waitcnt vmcnt(0)" ::: "memory");
  unsigned u2[8][8];
  #pragma unroll
  for (int ep = 0; ep < 8; ep++) {
    uint4 a = uv[ep * 2], b4 = uv[ep * 2 + 1];
    u2[ep][0] = a.x; u2[ep][1] = a.y; u2[ep][2] = a.z; u2[ep][3] = a.w;
    u2[ep][4] = b4.x; u2[ep][5] = b4.y; u2[ep][6] = b4.z; u2[ep][7] = b4.w;
  }

  h_lds[0][tid] = 0.0f;   // h_0 = 0
  float creg = 0.0f;
  const int b0 = rb & 1, b1 = (rb >> 1) & 1, b2v = (rb >> 2) & 1;

  for (int t = 0; t < T; t++) {
    #pragma unroll
    for (int ep = 0; ep < 8; ep++) {
      #pragma unroll
      for (int c = 0; c < 8; c++) asm volatile("" : "+v"(u2[ep][c]));  // pin
    }
    float xv0, xv1, xv2, xv3;
    if (gl) {  // xz for this unit's 4 gates (independent of h; hides in poll)
      const float* xp = &xz[(size_t)(t & 255) * 2048 + u0 + rb];
      xv0 = xp[0]; xv1 = xp[512]; xv2 = xp[1024]; xv3 = xp[1536];
    }
    const int par = t & 1;
    if (mypoll) {  // poll 4 consecutive words (batched loads, all in flight)
      uint64_t* hw = hb + ((size_t)par << 9) + tid * 4;
      const unsigned tt = (unsigned)t;
      for (;;) {
        uint64_t w0 = AL(hw), w1 = AL(hw + 1), w2 = AL(hw + 2), w3 = AL(hw + 3);
        if (((unsigned)(w0 >> 32) == tt) & ((unsigned)(w1 >> 32) == tt) &
            ((unsigned)(w2 >> 32) == tt) & ((unsigned)(w3 >> 32) == tt)) {
          h_lds[par][tid * 4 + 0] = __uint_as_float((unsigned)w0);
          h_lds[par][tid * 4 + 1] = __uint_as_float((unsigned)w1);
          h_lds[par][tid * 4 + 2] = __uint_as_float((unsigned)w2);
          h_lds[par][tid * 4 + 3] = __uint_as_float((unsigned)w3);
          break;
        }
      }
    }
    __syncthreads();  // h_lds[par] complete

    // matvec: rows {rb+64ep, rb+64ep+32} x 8 cols, packed-f16 dot2
    float zp[8];
    #pragma unroll
    for (int c = 0; c < 8; c++) zp[c] = 0.0f;
    #pragma unroll
    for (int ep = 0; ep < 8; ep++) {
      float hlo = h_lds[par][rb + 64 * ep];
      float hhi = h_lds[par][rb + 64 * ep + 32];
      f16x2 h2 = __builtin_amdgcn_cvt_pkrtz(hlo, hhi);
      #pragma unroll
      for (int c = 0; c < 8; c++) {
        U32H2 w; w.u = u2[ep][c];
        zp[c] = __builtin_amdgcn_fdot2(h2, w.h, zp[c], false);
      }
    }
    // split-butterfly reduce (9 shuffles), then redistribution
    float q[4];
    #pragma unroll
    for (int j = 0; j < 4; j++) {
      float send = b0 ? zp[2 * j] : zp[2 * j + 1];
      float recv = __shfl_xor(send, 1, 64);
      q[j] = (b0 ? zp[2 * j + 1] : zp[2 * j]) + recv;
    }
    float r2[2];
    #pragma unroll
    for (int j = 0; j < 2; j++) {
      float send = b1 ? q[2 * j] : q[2 * j + 1];
      float recv = __shfl_xor(send, 2, 64);
      r2[j] = (b1 ? q[2 * j + 1] : q[2 * j]) + recv;
    }
    float z;
    {
      float send = b2v ? r2[0] : r2[1];
      float recv = __shfl_xor(send, 4, 64);
      z = (b2v ? r2[1] : r2[0]) + recv;
    }
    z += __shfl_xor(z, 8, 64);
    z += __shfl_xor(z, 16, 64);
    float zf = __shfl(z, (lane & 32) + 2 + b0, 64);
    float zg = __shfl(z, (lane & 32) + 4 + b0, 64);
    float zo = __shfl(z, (lane & 32) + 6 + b0, 64);

    if (gl) {  // gates for unit u0+rb
      float ig = sigm(z + xv0);
      float fg = sigm(zf + xv1);
      float gg = tanh_fast(zg + xv2);
      float og = sigm(zo + xv3);
      creg = fg * creg + ig * gg;
      float h = og * tanh_fast(creg);
      uint64_t pk = ((uint64_t)(unsigned)(t + 1) << 32) | (uint64_t)__float_as_uint(h);
      __hip_atomic_store(&hb[((size_t)((t + 1) & 1) << 9) + u0 + rb], pk,
                         __ATOMIC_RELAXED, __HIP_MEMORY_SCOPE_AGENT);
      h_lds[(t + 1) & 1][u0 + rb] = h;   // own-WG shortcut
      hs[(size_t)t * 512 + u0 + rb] = f2bf(h);
    }
  }
}

// ---------------------------------------------------------------------------
// Kernel 4: logits = hs @ Wl + bl. 8-wave 128(M)x256(N) tile, K-step 32,
// bf16 MFMA 16x16x32. Wave w: wr=w>>2 (2 M-slabs), wc=w&3 (4 N-slabs),
// per-wave 64x64. Grid (125,16) = 2000 blocks. Output remap:
// gemm row t -> out row (t%256)*8 + t/256.
// ---------------------------------------------------------------------------
__global__ __launch_bounds__(512) void logits_kernel(
    const unsigned short* __restrict__ hs, const unsigned short* __restrict__ Wlt,
    const float* __restrict__ bl, float* __restrict__ out)
{
  __shared__ unsigned short As[128][40];  // [row][k] +8 pad
  __shared__ unsigned short Bs[256][40];  // [col][k] +8 pad
  const int tid = threadIdx.x;
  const int bx = blockIdx.x, by = blockIdx.y;
  const int lane = tid & 63, w = tid >> 6;
  const int wr = w >> 2, wc = w & 3;

  f32x4 acc[4][4];
  #pragma unroll
  for (int i = 0; i < 4; i++) {
    #pragma unroll
    for (int j = 0; j < 4; j++) acc[i][j] = (f32x4){0.0f, 0.0f, 0.0f, 0.0f};
  }

  for (int kk = 0; kk < 512; kk += 32) {
    {  // A: 128 rows x 32 k = 512 chunks of 16B, 1/thread
      int r = tid >> 2, c8 = (tid & 3) * 8;
      *(uint4*)&As[r][c8] = *(const uint4*)&hs[(size_t)(by * 128 + r) * 512 + kk + c8];
    }
    #pragma unroll
    for (int i = 0; i < 2; i++) {  // B: 256 rows x 32 k = 1024 chunks, 2/thread
      int chunk = tid * 2 + i;
      int r = chunk >> 2, c8 = (chunk & 3) * 8;
      *(uint4*)&Bs[r][c8] = *(const uint4*)&Wlt[(size_t)(bx * 256 + r) * 512 + kk + c8];
    }
    __syncthreads();
    short8 af[4], bf[4];
    #pragma unroll
    for (int fr = 0; fr < 4; fr++)
      af[fr] = *(const short8*)&As[wr * 64 + fr * 16 + (lane & 15)][(lane >> 4) * 8];
    #pragma unroll
    for (int fc = 0; fc < 4; fc++)
      bf[fc] = *(const short8*)&Bs[wc * 64 + fc * 16 + (lane & 15)][(lane >> 4) * 8];
    #pragma unroll
    for (int fr = 0; fr < 4; fr++) {
      #pragma unroll
      for (int fc = 0; fc < 4; fc++)
        acc[fr][fc] = __builtin_amdgcn_mfma_f32_16x16x32_bf16(af[fr], bf[fc], acc[fr][fc], 0, 0, 0);
    }
    __syncthreads();
  }

  #pragma unroll
  for (int fc = 0; fc < 4; fc++) {
    int col = bx * 256 + wc * 64 + fc * 16 + (lane & 15);
    float blv = bl[col];
    #pragma unroll
    for (int fr = 0; fr < 4; fr++) {
      int row0 = by * 128 + wr * 64 + fr * 16 + (lane >> 4) * 4;
      #pragma unroll
      for (int j = 0; j < 4; j++) {
        int row = row0 + j;
        int orow = (row & 255) * 8 + (row >> 8);
        out[(size_t)orow * VOCAB + col] = acc[fr][fc][j] + blv;
      }
    }
  }
}

// ---------------------------------------------------------------------------
extern "C" void kernel_launch(void* const* d_in, const int* in_sizes, int n_in,
                              void* d_out, int out_size, void* d_ws, size_t ws_size,
                              hipStream_t stream)
{
  const float* ctx = (const float*)d_in[0];
  const float* Wm  = (const float*)d_in[1];
  const float* bm  = (const float*)d_in[2];
  const float* W   = (const float*)d_in[3];
  const float* U   = (const float*)d_in[4];
  const float* b   = (const float*)d_in[5];
  const float* Wl  = (const float*)d_in[6];
  const float* bl  = (const float*)d_in[7];
  float* out = (float*)d_out;

  char* ws = (char*)d_ws;
  uint64_t* hb        = (uint64_t*)ws;                                   // 8 KB (2x512 u64)
  float* xz           = (float*)(ws + 65536);                            // 2 MB
  unsigned short* hs  = (unsigned short*)(ws + 65536 + (1 << 21));       // 2 MB
  unsigned* Upr       = (unsigned*)(ws + 65536 + (2 << 21));             // 2 MB
  unsigned short* Wlt = (unsigned short*)(ws + 65536 + (3 << 21));       // 32.77 MB

  hipMemsetAsync(hb, 0, 8192, stream);  // h_0 = 0 with tag 0 (both parities)
  prep_kernel<<<dim3(64), dim3(512), 0, stream>>>(ctx, Wm, bm, W, b, xz);
  uconv2_kernel<<<dim3(256), dim3(256), 0, stream>>>(U, Upr);
  wl_convert_kernel<<<dim3(125), dim3(256), 0, stream>>>(Wl, Wlt);

  void* args[] = { (void*)&xz, (void*)&Upr, (void*)&hb, (void*)&hs };
  hipLaunchCooperativeKernel((void*)lstm_kernel, dim3(NWG), dim3(512), args, 0, stream);

  logits_kernel<<<dim3(125, 16), dim3(512), 0, stream>>>(hs, Wlt, bl, out);
}